// Round 17
// baseline (272.276 us; speedup 1.0000x reference)
//
#include <hip/hip_runtime.h>
#include <hip/hip_bf16.h>

// MimiEuclideanCodebook — persistent-mt fp16-MFMA scan (A staged ONCE in LDS,
// nt-inner loop, B dbuf) with per-tile TOP-4 packed-key epilogue (no atomics,
// deterministic) + barrier-free LDS-staged np-bit-exact rescore + fused gather.
// scan: per (row, 128-col tile) store uint4 = four smallest packed keys
//   ((fkey(d2a) & ~0x7FF) | code); u32 sort == lex-(value,code) sort.
// rescore: thr = gm_trunc + DELTA. Candidates = stored codes with deq <= thr.
//   Tile rescan iff deq4 <= thr (>=4 codes within thr in one tile; rare).
//   np-exact fp32 FMA chains from LDS; lex-(value,idx) min => np argmin.

typedef float f32x4 __attribute__((ext_vector_type(4)));
typedef short s16x8 __attribute__((ext_vector_type(8)));
typedef _Float16 h16x8 __attribute__((ext_vector_type(8)));

#define D_DIM 256
#define N_ROWS 65536
#define K_CODES 2048
#define VQ_EPS 1e-5f
#define DELTA 0.25f

__device__ __forceinline__ short f16s(float f) {
    _Float16 h = (_Float16)f;                             // RTN
    return __builtin_bit_cast(short, h);
}
__device__ __forceinline__ unsigned fkey(float f) {       // order-preserving u32
    unsigned u = __float_as_uint(f);
    return u ^ (unsigned)(((int)u >> 31) | (int)0x80000000);
}
__device__ __forceinline__ float funkey(unsigned k) {
    unsigned u = (k & 0x80000000u) ? (k ^ 0x80000000u) : ~k;
    return __uint_as_float(u);
}
__device__ __forceinline__ void gload16(const void* g, void* l) {
    __builtin_amdgcn_global_load_lds(
        (const __attribute__((address_space(1))) void*)g,
        (__attribute__((address_space(3))) void*)l, 16, 0, 0);
}

// numpy pairwise sum of squares over 256 (verified round 4)
__device__ __forceinline__ void np_sumsq_16lane(const float* a, float* out, int g) {
#pragma clang fp contract(off)
    int j = g & 7, h = g >> 3;
    const float* p = a + h * 128;
    float t = p[j];
    float r = t * t;
#pragma unroll
    for (int i = 1; i < 16; ++i) { float v = p[j + 8 * i]; r += v * v; }
    r += __shfl_xor(r, 1);
    r += __shfl_xor(r, 2);
    r += __shfl_xor(r, 4);
    float other = __shfl_xor(r, 8);
    if (g == 0) *out = r + other;
}

// FUSED codebook prep: embed = es/clip(us) (IEEE div), fp16+swizzle eswz,
// np-pairwise e2 (through LDS; fp32 round-trip is bit-exact). One es read.
__global__ void prep_codebook(const float* __restrict__ es, const float* __restrict__ us,
                              float* __restrict__ embed, unsigned short* __restrict__ eswz,
                              float* __restrict__ e2) {
    __shared__ float le[8][256];
    const int tid = threadIdx.x;
    const int rloc = tid >> 5, idx = tid & 31;            // 8 rows/block, 32 lanes/row
    const int r = blockIdx.x * 8 + rloc;                  // 2048 rows
    const float u = fmaxf(us[r], VQ_EPS);
    f32x4 v0 = *(const f32x4*)&es[r * D_DIM + idx * 8];
    f32x4 v1 = *(const f32x4*)&es[r * D_DIM + idx * 8 + 4];
    f32x4 e0, e1;
#pragma unroll
    for (int j = 0; j < 4; ++j) { e0[j] = v0[j] / u; e1[j] = v1[j] / u; }
    *(f32x4*)&embed[r * D_DIM + idx * 8] = e0;
    *(f32x4*)&embed[r * D_DIM + idx * 8 + 4] = e1;
    *(f32x4*)&le[rloc][idx * 8] = e0;
    *(f32x4*)&le[rloc][idx * 8 + 4] = e1;
    int kc = idx >> 2, ss = idx & 3;
    int sd = ss ^ ((r >> 1) & 3);                         // swizzle involution
    s16x8 b;
#pragma unroll
    for (int j = 0; j < 4; ++j) { b[j] = f16s(e0[j]); b[j + 4] = f16s(e1[j]); }
    *(s16x8*)&eswz[r * 256 + kc * 32 + sd * 8] = b;
    __syncthreads();
    if (idx < 16) np_sumsq_16lane(&le[rloc][0], &e2[r], idx);
}

// FUSED: x fp16-swizzle + np-pairwise x2 (one HBM pass over x)
__global__ void prep_x(const float* __restrict__ x, unsigned short* __restrict__ dst,
                       float* __restrict__ x2) {
    int gid = blockIdx.x * 256 + threadIdx.x;             // 65536*32
    int r = gid >> 5, idx = gid & 31;
    int kc = idx >> 2, s = idx & 3;
    int k0 = kc * 32 + (s ^ ((r >> 1) & 3)) * 8;
    const float* p = x + r * D_DIM + k0;
    s16x8 v;
#pragma unroll
    for (int j = 0; j < 8; ++j) v[j] = f16s(p[j]);
    *(s16x8*)&dst[r * 256 + kc * 32 + s * 8] = v;
    if (idx < 16)                                         // L1-hot re-read
        np_sumsq_16lane(x + r * D_DIM, x2 + r, idx);
}

// ---- persistent-mt fp16 MFMA scan: A once in LDS, nt loop, top-4 keys -------
__launch_bounds__(256, 2)
__global__ void vq_scan(const unsigned short* __restrict__ xswz,
                        const unsigned short* __restrict__ eswz,
                        const float* __restrict__ e2, const float* __restrict__ x2,
                        uint4* __restrict__ keys) {
    __shared__ __align__(16) short lA[8][128][32];        // 64 KB, chunk-major
    __shared__ __align__(16) short lB[2][4096];           // 16 KB dbuf (128x32)

    const int mt = blockIdx.x;                            // 512 blocks, 1 per mt
    const int m_base = mt * 128;
    const int tid = threadIdx.x, lane = tid & 63, wid = tid >> 6;
    const int rb = wid * 32;                              // wave: rows rb..rb+31
    const int l15 = lane & 15, lg = lane >> 4;

    // ---- stage A panel ONCE: 64 KB, chunk-major [kc][row][slot] -------------
#pragma unroll
    for (int p = 0; p < 16; ++p) {
        int off = p * 4096 + tid * 16;                    // linear LDS bytes
        int kc = off >> 13;
        int w = off & 8191;
        int row = w >> 6, slot = (w >> 4) & 3;            // pre-permuted source
        gload16((const char*)xswz + (((size_t)(m_base + row)) << 9) + (kc << 6) + (slot << 4),
                (char*)&lA[0][0][0] + off);
    }
    auto stage_B = [&](int nt, int kc, int buf) {
#pragma unroll
        for (int i = 0; i < 2; ++i) {
            int off = i * 4096 + tid * 16;
            int row = off >> 6, slot = (off >> 4) & 3;
            gload16((const char*)eswz + (((size_t)(nt * 128 + row)) << 9) + (kc << 6) + (slot << 4),
                    (char*)&lB[buf][0] + off);
        }
    };
    stage_B(0, 0, 0);
    __syncthreads();                                      // drain A + B(0,0)

    f32x4 acc[2][8];
    int buf = 0;
#pragma unroll 1
    for (int nt = 0; nt < 16; ++nt) {
        const int n_base = nt * 128;
#pragma unroll
        for (int m = 0; m < 2; ++m)
#pragma unroll
            for (int n = 0; n < 8; ++n) { f32x4 z = {0.f, 0.f, 0.f, 0.f}; acc[m][n] = z; }

#pragma unroll 1
        for (int kc = 0; kc < 8; ++kc) {
            int s = nt * 8 + kc;
            if (s < 127) stage_B((s + 1) >> 3, (s + 1) & 7, buf ^ 1);
            {   // compute from resident A chunk + B buf
                const short* A = &lA[kc][0][0];
                const short* B = &lB[buf][0];
                h16x8 af[2], bf[8];
#pragma unroll
                for (int m = 0; m < 2; ++m) {
                    int R = rb + m * 16 + l15, sw = lg ^ ((R >> 1) & 3);
                    af[m] = __builtin_bit_cast(h16x8, *(const s16x8*)&A[R * 32 + sw * 8]);
                }
#pragma unroll
                for (int n = 0; n < 8; ++n) {
                    int R = n * 16 + l15, sw = lg ^ ((R >> 1) & 3);
                    bf[n] = __builtin_bit_cast(h16x8, *(const s16x8*)&B[R * 32 + sw * 8]);
                }
#pragma unroll
                for (int m = 0; m < 2; ++m)
#pragma unroll
                    for (int n = 0; n < 8; ++n)
                        acc[m][n] = __builtin_amdgcn_mfma_f32_16x16x32_f16(af[m], bf[n], acc[m][n], 0, 0, 0);
            }
            if (kc == 7) {
                // ---- epilogue for this nt: per-(row,tile) sorted top-4 ------
                // C/D layout (rounds 8/10 verified): col=n*16+l15, row=lg*4+j (+m*16)
                const int grow0 = m_base + rb + lg * 4;
                float e2v[8];
#pragma unroll
                for (int n = 0; n < 8; ++n) e2v[n] = e2[n_base + n * 16 + l15];
#pragma unroll
                for (int m = 0; m < 2; ++m) {
#pragma unroll
                    for (int j = 0; j < 4; ++j) {
                        int gr = grow0 + m * 16 + j;
                        float x2v = x2[gr];
                        unsigned k1 = 0xFFFFFFFFu, k2 = 0xFFFFFFFFu;
                        unsigned k3 = 0xFFFFFFFFu, k4 = 0xFFFFFFFFu;
#pragma unroll
                        for (int n = 0; n < 8; ++n) {
                            float d2 = (x2v - 2.0f * acc[m][n][j]) + e2v[n];
                            unsigned pk = (fkey(d2) & 0xFFFFF800u)
                                          | (unsigned)(n_base + n * 16 + l15);
                            unsigned a = min(pk, k1), b = max(pk, k1); k1 = a;
                            a = min(b, k2); b = max(b, k2); k2 = a;
                            a = min(b, k3); b = max(b, k3); k3 = a;
                            k4 = min(b, k4);
                        }
#pragma unroll
                        for (int s2 = 1; s2 < 16; s2 <<= 1) {   // bitonic 4-merge
                            unsigned o1 = __shfl_xor(k1, s2), o2 = __shfl_xor(k2, s2);
                            unsigned o3 = __shfl_xor(k3, s2), o4 = __shfl_xor(k4, s2);
                            unsigned c1 = min(k1, o4), c2 = min(k2, o3);
                            unsigned c3 = min(k3, o2), c4 = min(k4, o1);
                            unsigned t;
                            t = min(c1, c3); c3 = max(c1, c3); c1 = t;
                            t = min(c2, c4); c4 = max(c2, c4); c2 = t;
                            t = min(c1, c2); c2 = max(c1, c2); c1 = t;
                            t = min(c3, c4); c4 = max(c3, c4); c3 = t;
                            k1 = c1; k2 = c2; k3 = c3; k4 = c4;
                        }
                        if (l15 == 0) {
                            uint4 kq; kq.x = k1; kq.y = k2; kq.z = k3; kq.w = k4;
                            keys[gr * 16 + nt] = kq;
                        }
                    }
                }
            }
            __syncthreads();                              // drain B(s+1) + readers
            buf ^= 1;
        }
    }
}

// -- barrier-free LDS-staged np-exact rescore (wave per row) + fused gather ----
__launch_bounds__(256, 4)
__global__ void vq_rescore(const float* __restrict__ x, const float* __restrict__ embed,
                           const float* __restrict__ e2, const float* __restrict__ x2,
                           const uint4* __restrict__ keys,
                           const float* __restrict__ es, const float* __restrict__ us,
                           float* __restrict__ out) {
    __shared__ float lx[4][256];                          // per-wave x row
    __shared__ float le[4][8][260];                       // per-wave staged embeds
    __shared__ int lcode[4][64];                          // per-wave cand codes

    const int tid = threadIdx.x, w = tid >> 6, lane = tid & 63;
    const int r = blockIdx.x * 4 + w;
    const int t16 = lane & 15;
    const float x2v = x2[r];
    const unsigned long long lt = (1ull << lane) - 1ull;

    // stage x row (wave-private; wave-lockstep + in-order LDS => no barrier)
    *(f32x4*)&lx[w][lane * 4] = *(const f32x4*)&x[r * D_DIM + lane * 4];

    uint4 kq = keys[r * 16 + t16];                        // 4 copies per 16-group
    unsigned kmin = kq.x & 0xFFFFF800u;
#pragma unroll
    for (int s = 1; s < 16; s <<= 1) {                    // gm over 16 tiles
        unsigned ok = __shfl_xor(kmin, s);
        kmin = ok < kmin ? ok : kmin;
    }
    const float thr = funkey(kmin) + DELTA;

    // compact candidates (slot-major, deterministic ballot order)
    unsigned sv[4] = {kq.x, kq.y, kq.z, kq.w};
    int nc = 0;
#pragma unroll
    for (int s = 0; s < 4; ++s) {                         // static after unroll
        bool v = (lane < 16) && (funkey(sv[s] & 0xFFFFF800u) <= thr);
        unsigned long long b = __ballot(v);
        if (v) lcode[w][nc + __popcll(b & lt)] = (int)(sv[s] & 0x7FFu);
        nc += (int)__popcll(b);
    }
    bool resc = (lane < 16) && (funkey(kq.w & 0xFFFFF800u) <= thr);
    unsigned long long rmask = __ballot(resc);            // bits 0..15 = tiles

    float bv = __builtin_inff();
    int bi = 0x7FFFFFFF;
    auto lexmin = [&](float d2, int code) {
        if (d2 < bv || (d2 == bv && code < bi)) { bv = d2; bi = code; }
    };

#pragma unroll 1
    for (int g = 0; g < (nc + 7) >> 3; ++g) {             // wave-uniform nc
#pragma unroll
        for (int v = 0; v < 8; ++v) {                     // stage <=8 embed rows
            int idx = g * 8 + v;
            if (idx < nc) {
                int code = lcode[w][idx];
                *(f32x4*)&le[w][v][lane * 4] =
                    *(const f32x4*)&embed[code * D_DIM + lane * 4];
            }
        }
        int idx = g * 8 + lane;                           // lanes 0..7 run chains
        if (lane < 8 && idx < nc) {
            int code = lcode[w][idx];
            float t = 0.0f;
#pragma unroll 8
            for (int k4 = 0; k4 < 64; ++k4) {             // single chain, k ascending
                f32x4 a4 = *(const f32x4*)&lx[w][k4 * 4];     // broadcast
                f32x4 e4 = *(const f32x4*)&le[w][lane][k4 * 4];
                t = __builtin_fmaf(a4[0], e4[0], t);
                t = __builtin_fmaf(a4[1], e4[1], t);
                t = __builtin_fmaf(a4[2], e4[2], t);
                t = __builtin_fmaf(a4[3], e4[3], t);
            }
            lexmin((x2v - 2.0f * t) + e2[code], code);    // np op order
        }
    }

    // rare: >=4 codes within thr in one tile -> exact rescan of that tile
    while (rmask) {
        int t2 = __ffsll(rmask) - 1;
        rmask &= rmask - 1;
        int ca = t2 * 128 + lane, cb = ca + 64;
        float ta = 0.0f, tb = 0.0f;
#pragma unroll 8
        for (int k4 = 0; k4 < 64; ++k4) {                 // dual interleaved chains
            f32x4 a4 = *(const f32x4*)&lx[w][k4 * 4];
            f32x4 ea = *(const f32x4*)&embed[ca * D_DIM + k4 * 4];
            f32x4 eb = *(const f32x4*)&embed[cb * D_DIM + k4 * 4];
            ta = __builtin_fmaf(a4[0], ea[0], ta);
            tb = __builtin_fmaf(a4[0], eb[0], tb);
            ta = __builtin_fmaf(a4[1], ea[1], ta);
            tb = __builtin_fmaf(a4[1], eb[1], tb);
            ta = __builtin_fmaf(a4[2], ea[2], ta);
            tb = __builtin_fmaf(a4[2], eb[2], tb);
            ta = __builtin_fmaf(a4[3], ea[3], ta);
            tb = __builtin_fmaf(a4[3], eb[3], tb);
        }
        lexmin((x2v - 2.0f * ta) + e2[ca], ca);
        lexmin((x2v - 2.0f * tb) + e2[cb], cb);
    }

#pragma unroll
    for (int s = 1; s < 64; s <<= 1) {                    // 64-lane lex allreduce
        float ov = __shfl_xor(bv, s);
        int oi = __shfl_xor(bi, s);
        if (ov < bv || (ov == bv && oi < bi)) { bv = ov; bi = oi; }
    }
    if (lane == 0) out[r] = (float)bi;

    // fused gather: quantized[r] = es[bi]/max(us[bi],eps); 64 lanes x 4 floats
    float u = fmaxf(us[bi], VQ_EPS);
    f32x4 wv = *(const f32x4*)&es[bi * D_DIM + lane * 4];
    f32x4 o;
#pragma unroll
    for (int j = 0; j < 4; ++j) o[j] = wv[j] / u;         // IEEE div == np bitwise
    *(f32x4*)&out[N_ROWS + r * D_DIM + lane * 4] = o;
}

extern "C" void kernel_launch(void* const* d_in, const int* in_sizes, int n_in,
                              void* d_out, int out_size, void* d_ws, size_t ws_size,
                              hipStream_t stream) {
    const float* x = (const float*)d_in[0];               // [65536, 256]
    const float* es = (const float*)d_in[1];              // [2048, 256]
    const float* us = (const float*)d_in[2];              // [2048]
    float* out = (float*)d_out;

    char* w = (char*)d_ws;                                // total 53,747,712 B
    unsigned short* xswz = (unsigned short*)(w);                  // 33,554,432
    unsigned short* eswz = (unsigned short*)(w + 33554432);       //  1,048,576
    float* embed         = (float*)(w + 34603008);                //  2,097,152
    float* e2            = (float*)(w + 36700160);                //      8,192
    float* x2            = (float*)(w + 36708352);                //    262,144
    uint4* keys          = (uint4*)(w + 36970496);                // 16,777,216

    hipLaunchKernelGGL(prep_codebook, dim3(256), dim3(256), 0, stream,
                       es, us, embed, eswz, e2);
    hipLaunchKernelGGL(prep_x, dim3(8192), dim3(256), 0, stream, x, xswz, x2);
    hipLaunchKernelGGL(vq_scan, dim3(512), dim3(256), 0, stream,
                       xswz, eswz, e2, x2, keys);
    hipLaunchKernelGGL(vq_rescore, dim3(16384), dim3(256), 0, stream,
                       x, embed, e2, x2, keys, es, us, out);
}

// Round 18
// 230.010 us; speedup vs baseline: 1.1838x; 1.1838x over previous
//
#include <hip/hip_runtime.h>
#include <hip/hip_bf16.h>

// MimiEuclideanCodebook — SINGLE fp16-MFMA scan (gload_lds, SINGLE-buffer LDS
// for max occupancy) with per-tile TOP-4 packed-key epilogue (no atomics,
// deterministic) + barrier-free LDS-staged np-bit-exact rescore + fused gather.
// scan: per (row, 128-col tile) store uint4 = four smallest packed keys
//   ((fkey(d2a) & ~0x7FF) | code); u32 sort == lex-(value,code) sort.
// rescore: thr = gm_trunc + DELTA. Candidates = stored codes with deq <= thr.
//   Tile rescan iff deq4 <= thr (>=4 codes within thr in one tile; rare).
//   np-exact fp32 FMA chains from LDS; lex-(value,idx) min => np argmin.

typedef float f32x4 __attribute__((ext_vector_type(4)));
typedef short s16x8 __attribute__((ext_vector_type(8)));
typedef _Float16 h16x8 __attribute__((ext_vector_type(8)));

#define D_DIM 256
#define N_ROWS 65536
#define K_CODES 2048
#define VQ_EPS 1e-5f
#define DELTA 0.25f

__device__ __forceinline__ short f16s(float f) {
    _Float16 h = (_Float16)f;                             // RTN
    return __builtin_bit_cast(short, h);
}
__device__ __forceinline__ unsigned fkey(float f) {       // order-preserving u32
    unsigned u = __float_as_uint(f);
    return u ^ (unsigned)(((int)u >> 31) | (int)0x80000000);
}
__device__ __forceinline__ float funkey(unsigned k) {
    unsigned u = (k & 0x80000000u) ? (k ^ 0x80000000u) : ~k;
    return __uint_as_float(u);
}
__device__ __forceinline__ void gload16(const void* g, void* l) {
    __builtin_amdgcn_global_load_lds(
        (const __attribute__((address_space(1))) void*)g,
        (__attribute__((address_space(3))) void*)l, 16, 0, 0);
}

// numpy pairwise sum of squares over 256 (verified round 4)
__device__ __forceinline__ void np_sumsq_16lane(const float* a, float* out, int g) {
#pragma clang fp contract(off)
    int j = g & 7, h = g >> 3;
    const float* p = a + h * 128;
    float t = p[j];
    float r = t * t;
#pragma unroll
    for (int i = 1; i < 16; ++i) { float v = p[j + 8 * i]; r += v * v; }
    r += __shfl_xor(r, 1);
    r += __shfl_xor(r, 2);
    r += __shfl_xor(r, 4);
    float other = __shfl_xor(r, 8);
    if (g == 0) *out = r + other;
}

// FUSED codebook prep: embed = es/clip(us) (IEEE div), fp16+swizzle eswz,
// np-pairwise e2 (through LDS; fp32 round-trip is bit-exact). One es read.
__global__ void prep_codebook(const float* __restrict__ es, const float* __restrict__ us,
                              float* __restrict__ embed, unsigned short* __restrict__ eswz,
                              float* __restrict__ e2) {
    __shared__ float le[8][256];
    const int tid = threadIdx.x;
    const int rloc = tid >> 5, idx = tid & 31;            // 8 rows/block, 32 lanes/row
    const int r = blockIdx.x * 8 + rloc;                  // 2048 rows
    const float u = fmaxf(us[r], VQ_EPS);
    f32x4 v0 = *(const f32x4*)&es[r * D_DIM + idx * 8];
    f32x4 v1 = *(const f32x4*)&es[r * D_DIM + idx * 8 + 4];
    f32x4 e0, e1;
#pragma unroll
    for (int j = 0; j < 4; ++j) { e0[j] = v0[j] / u; e1[j] = v1[j] / u; }
    *(f32x4*)&embed[r * D_DIM + idx * 8] = e0;
    *(f32x4*)&embed[r * D_DIM + idx * 8 + 4] = e1;
    *(f32x4*)&le[rloc][idx * 8] = e0;
    *(f32x4*)&le[rloc][idx * 8 + 4] = e1;
    int kc = idx >> 2, ss = idx & 3;
    int sd = ss ^ ((r >> 1) & 3);                         // swizzle involution
    s16x8 b;
#pragma unroll
    for (int j = 0; j < 4; ++j) { b[j] = f16s(e0[j]); b[j + 4] = f16s(e1[j]); }
    *(s16x8*)&eswz[r * 256 + kc * 32 + sd * 8] = b;
    __syncthreads();
    if (idx < 16) np_sumsq_16lane(&le[rloc][0], &e2[r], idx);
}

// FUSED: x fp16-swizzle + np-pairwise x2 (one HBM pass over x)
__global__ void prep_x(const float* __restrict__ x, unsigned short* __restrict__ dst,
                       float* __restrict__ x2) {
    int gid = blockIdx.x * 256 + threadIdx.x;             // 65536*32
    int r = gid >> 5, idx = gid & 31;
    int kc = idx >> 2, s = idx & 3;
    int k0 = kc * 32 + (s ^ ((r >> 1) & 3)) * 8;
    const float* p = x + r * D_DIM + k0;
    s16x8 v;
#pragma unroll
    for (int j = 0; j < 8; ++j) v[j] = f16s(p[j]);
    *(s16x8*)&dst[r * 256 + kc * 32 + s * 8] = v;
    if (idx < 16)                                         // L1-hot re-read
        np_sumsq_16lane(x + r * D_DIM, x2 + r, idx);
}

// ---- single fp16 MFMA scan (single-buffer LDS, high occupancy) ---------------
__launch_bounds__(256, 2)
__global__ void vq_scan(const unsigned short* __restrict__ xswz,
                        const unsigned short* __restrict__ eswz,
                        const float* __restrict__ e2, const float* __restrict__ x2,
                        uint4* __restrict__ keys) {
    __shared__ __align__(16) short lA[4096];              // 8 KB (128 rows x 32 k)
    __shared__ __align__(16) short lB[4096];              // 8 KB

    const int bid = blockIdx.x;
    const int swz = (bid & 7) * 1024 + (bid >> 3);        // XCD-contiguous tiles
    const int mt = swz >> 4, nt = swz & 15;
    const int m_base = mt * 128, n_base = nt * 128;
    const int tid = threadIdx.x, lane = tid & 63, wid = tid >> 6;
    const int rb = wid * 32;                              // wave: rows rb..rb+31
    const int l15 = lane & 15, lg = lane >> 4;

    f32x4 acc[2][8];
#pragma unroll
    for (int m = 0; m < 2; ++m)
#pragma unroll
        for (int n = 0; n < 8; ++n) { f32x4 z = {0.f, 0.f, 0.f, 0.f}; acc[m][n] = z; }

    auto stage = [&](int kc) {
#pragma unroll
        for (int i = 0; i < 2; ++i) {
            int off = i * 4096 + wid * 1024 + lane * 16;  // linear LDS dest bytes
            int row = off >> 6, slot = (off >> 4) & 3;    // pre-permuted source
            gload16((const char*)xswz + (((size_t)(m_base + row)) << 9) + (kc << 6) + (slot << 4),
                    (char*)&lA[0] + off);
            gload16((const char*)eswz + (((size_t)(n_base + row)) << 9) + (kc << 6) + (slot << 4),
                    (char*)&lB[0] + off);
        }
    };
    auto compute = [&]() {
        h16x8 af[2], bf[8];
#pragma unroll
        for (int m = 0; m < 2; ++m) {
            int R = rb + m * 16 + l15, s = lg ^ ((R >> 1) & 3);
            af[m] = __builtin_bit_cast(h16x8, *(const s16x8*)&lA[R * 32 + s * 8]);
        }
#pragma unroll
        for (int n = 0; n < 8; ++n) {
            int R = n * 16 + l15, s = lg ^ ((R >> 1) & 3);
            bf[n] = __builtin_bit_cast(h16x8, *(const s16x8*)&lB[R * 32 + s * 8]);
        }
#pragma unroll
        for (int m = 0; m < 2; ++m)
#pragma unroll
            for (int n = 0; n < 8; ++n)
                acc[m][n] = __builtin_amdgcn_mfma_f32_16x16x32_f16(af[m], bf[n], acc[m][n], 0, 0, 0);
    };

#pragma unroll 1
    for (int kc = 0; kc < 8; ++kc) {
        stage(kc);                                        // issue loads
        __syncthreads();                                  // drain vmcnt, LDS ready
        compute();
        __syncthreads();                                  // readers done pre-overwrite
    }

    // epilogue: packed keys; per-lane sorted top-4 insert; one 4-step bitonic
    // pair-merge butterfly over 16 lanes. No dynamic register indexing.
    // C/D layout (rounds 8/10 verified): col = n*16 + l15, row = lg*4+j (+m*16)
    const int grow0 = m_base + rb + lg * 4;
    float e2v[8];
#pragma unroll
    for (int n = 0; n < 8; ++n) e2v[n] = e2[n_base + n * 16 + l15];

#pragma unroll
    for (int m = 0; m < 2; ++m) {
#pragma unroll
        for (int j = 0; j < 4; ++j) {
            int gr = grow0 + m * 16 + j;
            float x2v = x2[gr];
            unsigned k1 = 0xFFFFFFFFu, k2 = 0xFFFFFFFFu;
            unsigned k3 = 0xFFFFFFFFu, k4 = 0xFFFFFFFFu;
#pragma unroll
            for (int n = 0; n < 8; ++n) {
                float d2 = (x2v - 2.0f * acc[m][n][j]) + e2v[n];
                unsigned pk = (fkey(d2) & 0xFFFFF800u)
                              | (unsigned)(n_base + n * 16 + l15);
                unsigned a = min(pk, k1), b = max(pk, k1); k1 = a;   // sorted insert
                a = min(b, k2); b = max(b, k2); k2 = a;
                a = min(b, k3); b = max(b, k3); k3 = a;
                k4 = min(b, k4);
            }
#pragma unroll
            for (int s = 1; s < 16; s <<= 1) {            // bitonic 4-merge
                unsigned o1 = __shfl_xor(k1, s), o2 = __shfl_xor(k2, s);
                unsigned o3 = __shfl_xor(k3, s), o4 = __shfl_xor(k4, s);
                unsigned c1 = min(k1, o4), c2 = min(k2, o3);
                unsigned c3 = min(k3, o2), c4 = min(k4, o1);
                unsigned t;
                t = min(c1, c3); c3 = max(c1, c3); c1 = t;
                t = min(c2, c4); c4 = max(c2, c4); c2 = t;
                t = min(c1, c2); c2 = max(c1, c2); c1 = t;
                t = min(c3, c4); c4 = max(c3, c4); c3 = t;
                k1 = c1; k2 = c2; k3 = c3; k4 = c4;
            }
            if (l15 == 0) {
                uint4 kq; kq.x = k1; kq.y = k2; kq.z = k3; kq.w = k4;
                keys[gr * 16 + nt] = kq;
            }
        }
    }
}

// -- barrier-free LDS-staged np-exact rescore (wave per row) + fused gather ----
__launch_bounds__(256, 4)
__global__ void vq_rescore(const float* __restrict__ x, const float* __restrict__ embed,
                           const float* __restrict__ e2, const float* __restrict__ x2,
                           const uint4* __restrict__ keys,
                           const float* __restrict__ es, const float* __restrict__ us,
                           float* __restrict__ out) {
    __shared__ float lx[4][256];                          // per-wave x row
    __shared__ float le[4][8][260];                       // per-wave staged embeds
    __shared__ int lcode[4][64];                          // per-wave cand codes

    const int tid = threadIdx.x, w = tid >> 6, lane = tid & 63;
    const int r = blockIdx.x * 4 + w;
    const int t16 = lane & 15;
    const float x2v = x2[r];
    const unsigned long long lt = (1ull << lane) - 1ull;

    // stage x row (wave-private; wave-lockstep + in-order LDS => no barrier)
    *(f32x4*)&lx[w][lane * 4] = *(const f32x4*)&x[r * D_DIM + lane * 4];

    uint4 kq = keys[r * 16 + t16];                        // 4 copies per 16-group
    unsigned kmin = kq.x & 0xFFFFF800u;
#pragma unroll
    for (int s = 1; s < 16; s <<= 1) {                    // gm over 16 tiles
        unsigned ok = __shfl_xor(kmin, s);
        kmin = ok < kmin ? ok : kmin;
    }
    const float thr = funkey(kmin) + DELTA;

    // compact candidates (slot-major, deterministic ballot order)
    unsigned sv[4] = {kq.x, kq.y, kq.z, kq.w};
    int nc = 0;
#pragma unroll
    for (int s = 0; s < 4; ++s) {                         // static after unroll
        bool v = (lane < 16) && (funkey(sv[s] & 0xFFFFF800u) <= thr);
        unsigned long long b = __ballot(v);
        if (v) lcode[w][nc + __popcll(b & lt)] = (int)(sv[s] & 0x7FFu);
        nc += (int)__popcll(b);
    }
    bool resc = (lane < 16) && (funkey(kq.w & 0xFFFFF800u) <= thr);
    unsigned long long rmask = __ballot(resc);            // bits 0..15 = tiles

    float bv = __builtin_inff();
    int bi = 0x7FFFFFFF;
    auto lexmin = [&](float d2, int code) {
        if (d2 < bv || (d2 == bv && code < bi)) { bv = d2; bi = code; }
    };

#pragma unroll 1
    for (int g = 0; g < (nc + 7) >> 3; ++g) {             // wave-uniform nc
#pragma unroll
        for (int v = 0; v < 8; ++v) {                     // stage <=8 embed rows
            int idx = g * 8 + v;
            if (idx < nc) {
                int code = lcode[w][idx];
                *(f32x4*)&le[w][v][lane * 4] =
                    *(const f32x4*)&embed[code * D_DIM + lane * 4];
            }
        }
        int idx = g * 8 + lane;                           // lanes 0..7 run chains
        if (lane < 8 && idx < nc) {
            int code = lcode[w][idx];
            float t = 0.0f;
#pragma unroll 8
            for (int k4 = 0; k4 < 64; ++k4) {             // single chain, k ascending
                f32x4 a4 = *(const f32x4*)&lx[w][k4 * 4];     // broadcast
                f32x4 e4 = *(const f32x4*)&le[w][lane][k4 * 4];
                t = __builtin_fmaf(a4[0], e4[0], t);
                t = __builtin_fmaf(a4[1], e4[1], t);
                t = __builtin_fmaf(a4[2], e4[2], t);
                t = __builtin_fmaf(a4[3], e4[3], t);
            }
            lexmin((x2v - 2.0f * t) + e2[code], code);    // np op order
        }
    }

    // rare: >=4 codes within thr in one tile -> exact rescan of that tile
    while (rmask) {
        int t2 = __ffsll(rmask) - 1;
        rmask &= rmask - 1;
        int ca = t2 * 128 + lane, cb = ca + 64;
        float ta = 0.0f, tb = 0.0f;
#pragma unroll 8
        for (int k4 = 0; k4 < 64; ++k4) {                 // dual interleaved chains
            f32x4 a4 = *(const f32x4*)&lx[w][k4 * 4];
            f32x4 ea = *(const f32x4*)&embed[ca * D_DIM + k4 * 4];
            f32x4 eb = *(const f32x4*)&embed[cb * D_DIM + k4 * 4];
            ta = __builtin_fmaf(a4[0], ea[0], ta);
            tb = __builtin_fmaf(a4[0], eb[0], tb);
            ta = __builtin_fmaf(a4[1], ea[1], ta);
            tb = __builtin_fmaf(a4[1], eb[1], tb);
            ta = __builtin_fmaf(a4[2], ea[2], ta);
            tb = __builtin_fmaf(a4[2], eb[2], tb);
            ta = __builtin_fmaf(a4[3], ea[3], ta);
            tb = __builtin_fmaf(a4[3], eb[3], tb);
        }
        lexmin((x2v - 2.0f * ta) + e2[ca], ca);
        lexmin((x2v - 2.0f * tb) + e2[cb], cb);
    }

#pragma unroll
    for (int s = 1; s < 64; s <<= 1) {                    // 64-lane lex allreduce
        float ov = __shfl_xor(bv, s);
        int oi = __shfl_xor(bi, s);
        if (ov < bv || (ov == bv && oi < bi)) { bv = ov; bi = oi; }
    }
    if (lane == 0) out[r] = (float)bi;

    // fused gather: quantized[r] = es[bi]/max(us[bi],eps); 64 lanes x 4 floats
    float u = fmaxf(us[bi], VQ_EPS);
    f32x4 wv = *(const f32x4*)&es[bi * D_DIM + lane * 4];
    f32x4 o;
#pragma unroll
    for (int j = 0; j < 4; ++j) o[j] = wv[j] / u;         // IEEE div == np bitwise
    *(f32x4*)&out[N_ROWS + r * D_DIM + lane * 4] = o;
}

extern "C" void kernel_launch(void* const* d_in, const int* in_sizes, int n_in,
                              void* d_out, int out_size, void* d_ws, size_t ws_size,
                              hipStream_t stream) {
    const float* x = (const float*)d_in[0];               // [65536, 256]
    const float* es = (const float*)d_in[1];              // [2048, 256]
    const float* us = (const float*)d_in[2];              // [2048]
    float* out = (float*)d_out;

    char* w = (char*)d_ws;                                // total 53,747,712 B
    unsigned short* xswz = (unsigned short*)(w);                  // 33,554,432
    unsigned short* eswz = (unsigned short*)(w + 33554432);       //  1,048,576
    float* embed         = (float*)(w + 34603008);                //  2,097,152
    float* e2            = (float*)(w + 36700160);                //      8,192
    float* x2            = (float*)(w + 36708352);                //    262,144
    uint4* keys          = (uint4*)(w + 36970496);                // 16,777,216

    hipLaunchKernelGGL(prep_codebook, dim3(256), dim3(256), 0, stream,
                       es, us, embed, eswz, e2);
    hipLaunchKernelGGL(prep_x, dim3(8192), dim3(256), 0, stream, x, xswz, x2);
    hipLaunchKernelGGL(vq_scan, dim3(8192), dim3(256), 0, stream,
                       xswz, eswz, e2, x2, keys);
    hipLaunchKernelGGL(vq_rescore, dim3(16384), dim3(256), 0, stream,
                       x, embed, e2, x2, keys, es, us, out);
}

// Round 19
// 221.440 us; speedup vs baseline: 1.2296x; 1.0387x over previous
//
#include <hip/hip_runtime.h>
#include <hip/hip_bf16.h>

// MimiEuclideanCodebook — SINGLE fp16-MFMA scan (gload_lds dbuf) with
// per-tile TOP-4 packed-key epilogue (s = e2 - 2*xe basis; x2 is row-constant
// so ordering & within-row gaps identical) + barrier-free LDS-staged
// np-bit-exact rescore + fused gather.
// scan: per (row, 128-col tile) store uint4 = four smallest packed keys
//   ((fkey(s) & ~0x7FF) | code); u32 sort == lex-(value,code) sort.
//   Sorted insert via v_med3_u32 (1 min + 3 med3 per value).
// rescore (key-basis filtering, exact fp32 decisions): thr = gm_trunc + DELTA.
//   Candidates = stored codes with deq <= thr. Tile rescan iff deq4 <= thr.
//   np-exact fp32 FMA chains from LDS; lex-(value,idx) min => np argmin.

typedef float f32x4 __attribute__((ext_vector_type(4)));
typedef short s16x8 __attribute__((ext_vector_type(8)));
typedef _Float16 h16x8 __attribute__((ext_vector_type(8)));

#define D_DIM 256
#define N_ROWS 65536
#define K_CODES 2048
#define VQ_EPS 1e-5f
#define DELTA 0.25f

__device__ __forceinline__ short f16s(float f) {
    _Float16 h = (_Float16)f;                             // RTN
    return __builtin_bit_cast(short, h);
}
__device__ __forceinline__ unsigned fkey(float f) {       // order-preserving u32
    unsigned u = __float_as_uint(f);
    return u ^ (unsigned)(((int)u >> 31) | (int)0x80000000);
}
__device__ __forceinline__ float funkey(unsigned k) {
    unsigned u = (k & 0x80000000u) ? (k ^ 0x80000000u) : ~k;
    return __uint_as_float(u);
}
__device__ __forceinline__ unsigned med3u(unsigned a, unsigned b, unsigned c) {
    unsigned d;
    asm("v_med3_u32 %0, %1, %2, %3" : "=v"(d) : "v"(a), "v"(b), "v"(c));
    return d;
}
__device__ __forceinline__ void gload16(const void* g, void* l) {
    __builtin_amdgcn_global_load_lds(
        (const __attribute__((address_space(1))) void*)g,
        (__attribute__((address_space(3))) void*)l, 16, 0, 0);
}

// numpy pairwise sum of squares over 256 (verified round 4)
__device__ __forceinline__ void np_sumsq_16lane(const float* a, float* out, int g) {
#pragma clang fp contract(off)
    int j = g & 7, h = g >> 3;
    const float* p = a + h * 128;
    float t = p[j];
    float r = t * t;
#pragma unroll
    for (int i = 1; i < 16; ++i) { float v = p[j + 8 * i]; r += v * v; }
    r += __shfl_xor(r, 1);
    r += __shfl_xor(r, 2);
    r += __shfl_xor(r, 4);
    float other = __shfl_xor(r, 8);
    if (g == 0) *out = r + other;
}

// FUSED prep (one launch): blocks <256 = codebook (embed=es/clip(us) IEEE div,
// fp16+swizzle eswz, np-pairwise e2); blocks >=256 = x (fp16+swizzle xswz,
// np-pairwise x2). All numerics identical to verified rounds.
__global__ void prep_all(const float* __restrict__ es, const float* __restrict__ us,
                         const float* __restrict__ x,
                         float* __restrict__ embed, unsigned short* __restrict__ eswz,
                         float* __restrict__ e2,
                         unsigned short* __restrict__ xswz, float* __restrict__ x2) {
    __shared__ float le[8][256];
    const int tid = threadIdx.x;
    if (blockIdx.x < 256) {                               // ---- codebook path
        const int rloc = tid >> 5, idx = tid & 31;        // 8 rows/block
        const int r = blockIdx.x * 8 + rloc;              // 2048 rows
        const float u = fmaxf(us[r], VQ_EPS);
        f32x4 v0 = *(const f32x4*)&es[r * D_DIM + idx * 8];
        f32x4 v1 = *(const f32x4*)&es[r * D_DIM + idx * 8 + 4];
        f32x4 e0, e1;
#pragma unroll
        for (int j = 0; j < 4; ++j) { e0[j] = v0[j] / u; e1[j] = v1[j] / u; }
        *(f32x4*)&embed[r * D_DIM + idx * 8] = e0;
        *(f32x4*)&embed[r * D_DIM + idx * 8 + 4] = e1;
        *(f32x4*)&le[rloc][idx * 8] = e0;
        *(f32x4*)&le[rloc][idx * 8 + 4] = e1;
        int kc = idx >> 2, ss = idx & 3;
        int sd = ss ^ ((r >> 1) & 3);                     // swizzle involution
        s16x8 b;
#pragma unroll
        for (int j = 0; j < 4; ++j) { b[j] = f16s(e0[j]); b[j + 4] = f16s(e1[j]); }
        *(s16x8*)&eswz[r * 256 + kc * 32 + sd * 8] = b;
        __syncthreads();
        if (idx < 16) np_sumsq_16lane(&le[rloc][0], &e2[r], idx);
    } else {                                              // ---- x path
        int gid = (blockIdx.x - 256) * 256 + tid;         // 65536*32
        int r = gid >> 5, idx = gid & 31;
        int kc = idx >> 2, s = idx & 3;
        int k0 = kc * 32 + (s ^ ((r >> 1) & 3)) * 8;
        const float* p = x + r * D_DIM + k0;
        s16x8 v;
#pragma unroll
        for (int j = 0; j < 8; ++j) v[j] = f16s(p[j]);
        *(s16x8*)&xswz[r * 256 + kc * 32 + s * 8] = v;
        if (idx < 16)                                     // L1-hot re-read
            np_sumsq_16lane(x + r * D_DIM, x2 + r, idx);
    }
}

// ---- single fp16 MFMA scan (dbuf gload_lds) — s-basis top-4 keys ------------
__launch_bounds__(256, 2)
__global__ void vq_scan(const unsigned short* __restrict__ xswz,
                        const unsigned short* __restrict__ eswz,
                        const float* __restrict__ e2,
                        uint4* __restrict__ keys) {
    __shared__ __align__(16) short lds[2][2][4096];       // [buf][A/B][8KB]

    const int bid = blockIdx.x;
    const int swz = (bid & 7) * 1024 + (bid >> 3);        // XCD-contiguous tiles
    const int mt = swz >> 4, nt = swz & 15;
    const int m_base = mt * 128, n_base = nt * 128;
    const int tid = threadIdx.x, lane = tid & 63, wid = tid >> 6;
    const int rb = wid * 32;                              // wave: rows rb..rb+31
    const int l15 = lane & 15, lg = lane >> 4;

    f32x4 acc[2][8];
#pragma unroll
    for (int m = 0; m < 2; ++m)
#pragma unroll
        for (int n = 0; n < 8; ++n) { f32x4 z = {0.f, 0.f, 0.f, 0.f}; acc[m][n] = z; }

    auto stage = [&](int buf, int kc) {
#pragma unroll
        for (int i = 0; i < 2; ++i) {
            int off = i * 4096 + wid * 1024 + lane * 16;  // linear LDS dest bytes
            int row = off >> 6, slot = (off >> 4) & 3;    // pre-permuted source
            gload16((const char*)xswz + (((size_t)(m_base + row)) << 9) + (kc << 6) + (slot << 4),
                    (char*)&lds[buf][0][0] + off);
            gload16((const char*)eswz + (((size_t)(n_base + row)) << 9) + (kc << 6) + (slot << 4),
                    (char*)&lds[buf][1][0] + off);
        }
    };
    auto compute = [&](int buf) {
        const short* A = &lds[buf][0][0];
        const short* B = &lds[buf][1][0];
        h16x8 af[2], bf[8];
#pragma unroll
        for (int m = 0; m < 2; ++m) {
            int R = rb + m * 16 + l15, s = lg ^ ((R >> 1) & 3);
            af[m] = __builtin_bit_cast(h16x8, *(const s16x8*)&A[R * 32 + s * 8]);
        }
#pragma unroll
        for (int n = 0; n < 8; ++n) {
            int R = n * 16 + l15, s = lg ^ ((R >> 1) & 3);
            bf[n] = __builtin_bit_cast(h16x8, *(const s16x8*)&B[R * 32 + s * 8]);
        }
#pragma unroll
        for (int m = 0; m < 2; ++m)
#pragma unroll
            for (int n = 0; n < 8; ++n)
                acc[m][n] = __builtin_amdgcn_mfma_f32_16x16x32_f16(af[m], bf[n], acc[m][n], 0, 0, 0);
    };

    stage(0, 0);
    __syncthreads();
#pragma unroll 1
    for (int kc = 0; kc < 8; ++kc) {
        if (kc < 7) stage((kc + 1) & 1, kc + 1);          // loads fly under compute
        compute(kc & 1);
        __syncthreads();                                  // drain gload + readers done
    }

    // epilogue: s = fma(-2, xe, e2) (x2 dropped: row-constant shift preserves
    // order and within-row gaps); packed keys; med3-insert top-4; one 4-step
    // bitonic pair-merge butterfly over 16 lanes.
    // C/D layout (rounds 8/10 verified): col = n*16 + l15, row = lg*4+j (+m*16)
    const int grow0 = m_base + rb + lg * 4;
    float e2v[8];
#pragma unroll
    for (int n = 0; n < 8; ++n) e2v[n] = e2[n_base + n * 16 + l15];

#pragma unroll
    for (int m = 0; m < 2; ++m) {
#pragma unroll
        for (int j = 0; j < 4; ++j) {
            int gr = grow0 + m * 16 + j;
            unsigned k1 = 0xFFFFFFFFu, k2 = 0xFFFFFFFFu;
            unsigned k3 = 0xFFFFFFFFu, k4 = 0xFFFFFFFFu;
#pragma unroll
            for (int n = 0; n < 8; ++n) {
                float sv = __builtin_fmaf(-2.0f, acc[m][n][j], e2v[n]);
                unsigned pk = (fkey(sv) & 0xFFFFF800u)
                              | (unsigned)(n_base + n * 16 + l15);
                unsigned n1 = min(pk, k1);                // med3 sorted insert
                unsigned n2 = med3u(pk, k1, k2);
                unsigned n3 = med3u(pk, k2, k3);
                unsigned n4 = med3u(pk, k3, k4);
                k1 = n1; k2 = n2; k3 = n3; k4 = n4;
            }
#pragma unroll
            for (int s = 1; s < 16; s <<= 1) {            // bitonic 4-merge
                unsigned o1 = __shfl_xor(k1, s), o2 = __shfl_xor(k2, s);
                unsigned o3 = __shfl_xor(k3, s), o4 = __shfl_xor(k4, s);
                unsigned c1 = min(k1, o4), c2 = min(k2, o3);
                unsigned c3 = min(k3, o2), c4 = min(k4, o1);
                unsigned t;
                t = min(c1, c3); c3 = max(c1, c3); c1 = t;
                t = min(c2, c4); c4 = max(c2, c4); c2 = t;
                t = min(c1, c2); c2 = max(c1, c2); c1 = t;
                t = min(c3, c4); c4 = max(c3, c4); c3 = t;
                k1 = c1; k2 = c2; k3 = c3; k4 = c4;
            }
            if (l15 == 0) {
                uint4 kq; kq.x = k1; kq.y = k2; kq.z = k3; kq.w = k4;
                keys[gr * 16 + nt] = kq;
            }
        }
    }
}

// -- barrier-free LDS-staged np-exact rescore (wave per row) + fused gather ----
__launch_bounds__(256, 4)
__global__ void vq_rescore(const float* __restrict__ x, const float* __restrict__ embed,
                           const float* __restrict__ e2, const float* __restrict__ x2,
                           const uint4* __restrict__ keys,
                           const float* __restrict__ es, const float* __restrict__ us,
                           float* __restrict__ out) {
    __shared__ float lx[4][256];                          // per-wave x row
    __shared__ float le[4][8][260];                       // per-wave staged embeds
    __shared__ int lcode[4][64];                          // per-wave cand codes

    const int tid = threadIdx.x, w = tid >> 6, lane = tid & 63;
    const int r = blockIdx.x * 4 + w;
    const int t16 = lane & 15;
    const float x2v = x2[r];
    const unsigned long long lt = (1ull << lane) - 1ull;

    // stage x row (wave-private; wave-lockstep + in-order LDS => no barrier)
    *(f32x4*)&lx[w][lane * 4] = *(const f32x4*)&x[r * D_DIM + lane * 4];

    uint4 kq = keys[r * 16 + t16];                        // 4 copies per 16-group
    unsigned kmin = kq.x & 0xFFFFF800u;
#pragma unroll
    for (int s = 1; s < 16; s <<= 1) {                    // gm over 16 tiles
        unsigned ok = __shfl_xor(kmin, s);
        kmin = ok < kmin ? ok : kmin;
    }
    const float thr = funkey(kmin) + DELTA;               // key-basis threshold

    // compact candidates (slot-major, deterministic ballot order)
    unsigned sv[4] = {kq.x, kq.y, kq.z, kq.w};
    int nc = 0;
#pragma unroll
    for (int s = 0; s < 4; ++s) {                         // static after unroll
        bool v = (lane < 16) && (funkey(sv[s] & 0xFFFFF800u) <= thr);
        unsigned long long b = __ballot(v);
        if (v) lcode[w][nc + __popcll(b & lt)] = (int)(sv[s] & 0x7FFu);
        nc += (int)__popcll(b);
    }
    bool resc = (lane < 16) && (funkey(kq.w & 0xFFFFF800u) <= thr);
    unsigned long long rmask = __ballot(resc);            // bits 0..15 = tiles

    float bv = __builtin_inff();
    int bi = 0x7FFFFFFF;
    auto lexmin = [&](float d2, int code) {
        if (d2 < bv || (d2 == bv && code < bi)) { bv = d2; bi = code; }
    };

#pragma unroll 1
    for (int g = 0; g < (nc + 7) >> 3; ++g) {             // wave-uniform nc
#pragma unroll
        for (int v = 0; v < 8; ++v) {                     // stage <=8 embed rows
            int idx = g * 8 + v;
            if (idx < nc) {
                int code = lcode[w][idx];
                *(f32x4*)&le[w][v][lane * 4] =
                    *(const f32x4*)&embed[code * D_DIM + lane * 4];
            }
        }
        int idx = g * 8 + lane;                           // lanes 0..7 run chains
        if (lane < 8 && idx < nc) {
            int code = lcode[w][idx];
            float t = 0.0f;
#pragma unroll 8
            for (int k4 = 0; k4 < 64; ++k4) {             // single chain, k ascending
                f32x4 a4 = *(const f32x4*)&lx[w][k4 * 4];     // broadcast
                f32x4 e4 = *(const f32x4*)&le[w][lane][k4 * 4];
                t = __builtin_fmaf(a4[0], e4[0], t);
                t = __builtin_fmaf(a4[1], e4[1], t);
                t = __builtin_fmaf(a4[2], e4[2], t);
                t = __builtin_fmaf(a4[3], e4[3], t);
            }
            lexmin((x2v - 2.0f * t) + e2[code], code);    // np op order
        }
    }

    // rare: >=4 codes within thr in one tile -> exact rescan of that tile
    while (rmask) {
        int t2 = __ffsll(rmask) - 1;
        rmask &= rmask - 1;
        int ca = t2 * 128 + lane, cb = ca + 64;
        float ta = 0.0f, tb = 0.0f;
#pragma unroll 8
        for (int k4 = 0; k4 < 64; ++k4) {                 // dual interleaved chains
            f32x4 a4 = *(const f32x4*)&lx[w][k4 * 4];
            f32x4 ea = *(const f32x4*)&embed[ca * D_DIM + k4 * 4];
            f32x4 eb = *(const f32x4*)&embed[cb * D_DIM + k4 * 4];
            ta = __builtin_fmaf(a4[0], ea[0], ta);
            tb = __builtin_fmaf(a4[0], eb[0], tb);
            ta = __builtin_fmaf(a4[1], ea[1], ta);
            tb = __builtin_fmaf(a4[1], eb[1], tb);
            ta = __builtin_fmaf(a4[2], ea[2], ta);
            tb = __builtin_fmaf(a4[2], eb[2], tb);
            ta = __builtin_fmaf(a4[3], ea[3], ta);
            tb = __builtin_fmaf(a4[3], eb[3], tb);
        }
        lexmin((x2v - 2.0f * ta) + e2[ca], ca);
        lexmin((x2v - 2.0f * tb) + e2[cb], cb);
    }

#pragma unroll
    for (int s = 1; s < 64; s <<= 1) {                    // 64-lane lex allreduce
        float ov = __shfl_xor(bv, s);
        int oi = __shfl_xor(bi, s);
        if (ov < bv || (ov == bv && oi < bi)) { bv = ov; bi = oi; }
    }
    if (lane == 0) out[r] = (float)bi;

    // fused gather: quantized[r] = es[bi]/max(us[bi],eps); 64 lanes x 4 floats
    float u = fmaxf(us[bi], VQ_EPS);
    f32x4 wv = *(const f32x4*)&es[bi * D_DIM + lane * 4];
    f32x4 o;
#pragma unroll
    for (int j = 0; j < 4; ++j) o[j] = wv[j] / u;         // IEEE div == np bitwise
    *(f32x4*)&out[N_ROWS + r * D_DIM + lane * 4] = o;
}

extern "C" void kernel_launch(void* const* d_in, const int* in_sizes, int n_in,
                              void* d_out, int out_size, void* d_ws, size_t ws_size,
                              hipStream_t stream) {
    const float* x = (const float*)d_in[0];               // [65536, 256]
    const float* es = (const float*)d_in[1];              // [2048, 256]
    const float* us = (const float*)d_in[2];              // [2048]
    float* out = (float*)d_out;

    char* w = (char*)d_ws;                                // total 53,747,712 B
    unsigned short* xswz = (unsigned short*)(w);                  // 33,554,432
    unsigned short* eswz = (unsigned short*)(w + 33554432);       //  1,048,576
    float* embed         = (float*)(w + 34603008);                //  2,097,152
    float* e2            = (float*)(w + 36700160);                //      8,192
    float* x2            = (float*)(w + 36708352);                //    262,144
    uint4* keys          = (uint4*)(w + 36970496);                // 16,777,216

    hipLaunchKernelGGL(prep_all, dim3(8448), dim3(256), 0, stream,
                       es, us, x, embed, eswz, e2, xswz, x2);
    hipLaunchKernelGGL(vq_scan, dim3(8192), dim3(256), 0, stream,
                       xswz, eswz, e2, keys);
    hipLaunchKernelGGL(vq_rescore, dim3(16384), dim3(256), 0, stream,
                       x, embed, e2, x2, keys, es, us, out);
}

// Round 20
// 207.064 us; speedup vs baseline: 1.3149x; 1.0694x over previous
//
#include <hip/hip_runtime.h>
#include <hip/hip_bf16.h>

// MimiEuclideanCodebook — SINGLE fp16-MFMA scan (gload_lds dbuf) with
// per-tile TOP-4 packed-key epilogue (s = e2 - 2*xe basis) reduced via
// DPP row_ror rotate-merge (VALU pipe, no LDS-latency chains) +
// barrier-free LDS-staged np-bit-exact rescore + fused gather.
// scan: per (row, 128-col tile) store uint4 = four smallest packed keys
//   ((fkey(s) & ~0x7FF) | code). Top-4-of-union is a semilattice => rotate-
//   reduce (ror 8,4,2,1 over the 16-lane row) gives the same unique top-4 as
//   an xor butterfly — deterministic.
// rescore (key-basis filtering, exact fp32 decisions): thr = gm_trunc + DELTA.
//   Candidates = stored codes with deq <= thr. Tile rescan iff deq4 <= thr.
//   np-exact fp32 FMA chains from LDS; lex-(value,idx) min => np argmin.

typedef float f32x4 __attribute__((ext_vector_type(4)));
typedef short s16x8 __attribute__((ext_vector_type(8)));
typedef _Float16 h16x8 __attribute__((ext_vector_type(8)));

#define D_DIM 256
#define N_ROWS 65536
#define K_CODES 2048
#define VQ_EPS 1e-5f
#define DELTA 0.25f

__device__ __forceinline__ short f16s(float f) {
    _Float16 h = (_Float16)f;                             // RTN
    return __builtin_bit_cast(short, h);
}
__device__ __forceinline__ unsigned fkey(float f) {       // order-preserving u32
    unsigned u = __float_as_uint(f);
    return u ^ (unsigned)(((int)u >> 31) | (int)0x80000000);
}
__device__ __forceinline__ float funkey(unsigned k) {
    unsigned u = (k & 0x80000000u) ? (k ^ 0x80000000u) : ~k;
    return __uint_as_float(u);
}
__device__ __forceinline__ unsigned med3u(unsigned a, unsigned b, unsigned c) {
    unsigned d;
    asm("v_med3_u32 %0, %1, %2, %3" : "=v"(d) : "v"(a), "v"(b), "v"(c));
    return d;
}
__device__ __forceinline__ void gload16(const void* g, void* l) {
    __builtin_amdgcn_global_load_lds(
        (const __attribute__((address_space(1))) void*)g,
        (__attribute__((address_space(3))) void*)l, 16, 0, 0);
}

// DPP row_ror:N within each 16-lane row (VALU pipe; ctrl 0x120+N)
#define DPP_ROR(v, N) \
    ((unsigned)__builtin_amdgcn_update_dpp((int)(v), (int)(v), 0x120 + (N), 0xF, 0xF, true))

// numpy pairwise sum of squares over 256 (verified round 4)
__device__ __forceinline__ void np_sumsq_16lane(const float* a, float* out, int g) {
#pragma clang fp contract(off)
    int j = g & 7, h = g >> 3;
    const float* p = a + h * 128;
    float t = p[j];
    float r = t * t;
#pragma unroll
    for (int i = 1; i < 16; ++i) { float v = p[j + 8 * i]; r += v * v; }
    r += __shfl_xor(r, 1);
    r += __shfl_xor(r, 2);
    r += __shfl_xor(r, 4);
    float other = __shfl_xor(r, 8);
    if (g == 0) *out = r + other;
}

// FUSED prep (one launch): blocks <256 = codebook (embed=es/clip(us) IEEE div,
// fp16+swizzle eswz, np-pairwise e2); blocks >=256 = x (fp16+swizzle xswz,
// np-pairwise x2). All numerics identical to verified rounds.
__global__ void prep_all(const float* __restrict__ es, const float* __restrict__ us,
                         const float* __restrict__ x,
                         float* __restrict__ embed, unsigned short* __restrict__ eswz,
                         float* __restrict__ e2,
                         unsigned short* __restrict__ xswz, float* __restrict__ x2) {
    __shared__ float le[8][256];
    const int tid = threadIdx.x;
    if (blockIdx.x < 256) {                               // ---- codebook path
        const int rloc = tid >> 5, idx = tid & 31;        // 8 rows/block
        const int r = blockIdx.x * 8 + rloc;              // 2048 rows
        const float u = fmaxf(us[r], VQ_EPS);
        f32x4 v0 = *(const f32x4*)&es[r * D_DIM + idx * 8];
        f32x4 v1 = *(const f32x4*)&es[r * D_DIM + idx * 8 + 4];
        f32x4 e0, e1;
#pragma unroll
        for (int j = 0; j < 4; ++j) { e0[j] = v0[j] / u; e1[j] = v1[j] / u; }
        *(f32x4*)&embed[r * D_DIM + idx * 8] = e0;
        *(f32x4*)&embed[r * D_DIM + idx * 8 + 4] = e1;
        *(f32x4*)&le[rloc][idx * 8] = e0;
        *(f32x4*)&le[rloc][idx * 8 + 4] = e1;
        int kc = idx >> 2, ss = idx & 3;
        int sd = ss ^ ((r >> 1) & 3);                     // swizzle involution
        s16x8 b;
#pragma unroll
        for (int j = 0; j < 4; ++j) { b[j] = f16s(e0[j]); b[j + 4] = f16s(e1[j]); }
        *(s16x8*)&eswz[r * 256 + kc * 32 + sd * 8] = b;
        __syncthreads();
        if (idx < 16) np_sumsq_16lane(&le[rloc][0], &e2[r], idx);
    } else {                                              // ---- x path
        int gid = (blockIdx.x - 256) * 256 + tid;         // 65536*32
        int r = gid >> 5, idx = gid & 31;
        int kc = idx >> 2, s = idx & 3;
        int k0 = kc * 32 + (s ^ ((r >> 1) & 3)) * 8;
        const float* p = x + r * D_DIM + k0;
        s16x8 v;
#pragma unroll
        for (int j = 0; j < 8; ++j) v[j] = f16s(p[j]);
        *(s16x8*)&xswz[r * 256 + kc * 32 + s * 8] = v;
        if (idx < 16)                                     // L1-hot re-read
            np_sumsq_16lane(x + r * D_DIM, x2 + r, idx);
    }
}

// ---- single fp16 MFMA scan (dbuf gload_lds) — s-basis top-4, DPP merge ------
__launch_bounds__(256, 2)
__global__ void vq_scan(const unsigned short* __restrict__ xswz,
                        const unsigned short* __restrict__ eswz,
                        const float* __restrict__ e2,
                        uint4* __restrict__ keys) {
    __shared__ __align__(16) short lds[2][2][4096];       // [buf][A/B][8KB]

    const int bid = blockIdx.x;
    const int swz = (bid & 7) * 1024 + (bid >> 3);        // XCD-contiguous tiles
    const int mt = swz >> 4, nt = swz & 15;
    const int m_base = mt * 128, n_base = nt * 128;
    const int tid = threadIdx.x, lane = tid & 63, wid = tid >> 6;
    const int rb = wid * 32;                              // wave: rows rb..rb+31
    const int l15 = lane & 15, lg = lane >> 4;

    f32x4 acc[2][8];
#pragma unroll
    for (int m = 0; m < 2; ++m)
#pragma unroll
        for (int n = 0; n < 8; ++n) { f32x4 z = {0.f, 0.f, 0.f, 0.f}; acc[m][n] = z; }

    auto stage = [&](int buf, int kc) {
#pragma unroll
        for (int i = 0; i < 2; ++i) {
            int off = i * 4096 + wid * 1024 + lane * 16;  // linear LDS dest bytes
            int row = off >> 6, slot = (off >> 4) & 3;    // pre-permuted source
            gload16((const char*)xswz + (((size_t)(m_base + row)) << 9) + (kc << 6) + (slot << 4),
                    (char*)&lds[buf][0][0] + off);
            gload16((const char*)eswz + (((size_t)(n_base + row)) << 9) + (kc << 6) + (slot << 4),
                    (char*)&lds[buf][1][0] + off);
        }
    };
    auto compute = [&](int buf) {
        const short* A = &lds[buf][0][0];
        const short* B = &lds[buf][1][0];
        h16x8 af[2], bf[8];
#pragma unroll
        for (int m = 0; m < 2; ++m) {
            int R = rb + m * 16 + l15, s = lg ^ ((R >> 1) & 3);
            af[m] = __builtin_bit_cast(h16x8, *(const s16x8*)&A[R * 32 + s * 8]);
        }
#pragma unroll
        for (int n = 0; n < 8; ++n) {
            int R = n * 16 + l15, s = lg ^ ((R >> 1) & 3);
            bf[n] = __builtin_bit_cast(h16x8, *(const s16x8*)&B[R * 32 + s * 8]);
        }
#pragma unroll
        for (int m = 0; m < 2; ++m)
#pragma unroll
            for (int n = 0; n < 8; ++n)
                acc[m][n] = __builtin_amdgcn_mfma_f32_16x16x32_f16(af[m], bf[n], acc[m][n], 0, 0, 0);
    };

    stage(0, 0);
    __syncthreads();
#pragma unroll 1
    for (int kc = 0; kc < 8; ++kc) {
        if (kc < 7) stage((kc + 1) & 1, kc + 1);          // loads fly under compute
        compute(kc & 1);
        __syncthreads();                                  // drain gload + readers done
    }

    // epilogue: s = fma(-2, xe, e2) (x2 dropped: row-constant shift preserves
    // order and within-row gaps); packed keys; med3-insert top-4; rotate-merge
    // via DPP row_ror {8,4,2,1} (semilattice => same unique top-4, no LDS).
    // C/D layout (rounds 8/10 verified): col = n*16 + l15, row = lg*4+j (+m*16)
    const int grow0 = m_base + rb + lg * 4;
    float e2v[8];
#pragma unroll
    for (int n = 0; n < 8; ++n) e2v[n] = e2[n_base + n * 16 + l15];

#pragma unroll
    for (int m = 0; m < 2; ++m) {
#pragma unroll
        for (int j = 0; j < 4; ++j) {
            int gr = grow0 + m * 16 + j;
            unsigned k1 = 0xFFFFFFFFu, k2 = 0xFFFFFFFFu;
            unsigned k3 = 0xFFFFFFFFu, k4 = 0xFFFFFFFFu;
#pragma unroll
            for (int n = 0; n < 8; ++n) {
                float sv = __builtin_fmaf(-2.0f, acc[m][n][j], e2v[n]);
                unsigned pk = (fkey(sv) & 0xFFFFF800u)
                              | (unsigned)(n_base + n * 16 + l15);
                unsigned n1 = min(pk, k1);                // med3 sorted insert
                unsigned n2 = med3u(pk, k1, k2);
                unsigned n3 = med3u(pk, k2, k3);
                unsigned n4 = med3u(pk, k3, k4);
                k1 = n1; k2 = n2; k3 = n3; k4 = n4;
            }
#define MERGE_STEP(RR)                                                         \
            {                                                                  \
                unsigned o1 = DPP_ROR(k1, RR), o2 = DPP_ROR(k2, RR);           \
                unsigned o3 = DPP_ROR(k3, RR), o4 = DPP_ROR(k4, RR);           \
                unsigned c1 = min(k1, o4), c2 = min(k2, o3);                   \
                unsigned c3 = min(k3, o2), c4 = min(k4, o1);                   \
                unsigned t;                                                    \
                t = min(c1, c3); c3 = max(c1, c3); c1 = t;                     \
                t = min(c2, c4); c4 = max(c2, c4); c2 = t;                     \
                t = min(c1, c2); c2 = max(c1, c2); c1 = t;                     \
                t = min(c3, c4); c4 = max(c3, c4); c3 = t;                     \
                k1 = c1; k2 = c2; k3 = c3; k4 = c4;                            \
            }
            MERGE_STEP(8)
            MERGE_STEP(4)
            MERGE_STEP(2)
            MERGE_STEP(1)
#undef MERGE_STEP
            if (l15 == 0) {
                uint4 kq; kq.x = k1; kq.y = k2; kq.z = k3; kq.w = k4;
                keys[gr * 16 + nt] = kq;
            }
        }
    }
}

// -- barrier-free LDS-staged np-exact rescore (wave per row) + fused gather ----
__launch_bounds__(256, 4)
__global__ void vq_rescore(const float* __restrict__ x, const float* __restrict__ embed,
                           const float* __restrict__ e2, const float* __restrict__ x2,
                           const uint4* __restrict__ keys,
                           const float* __restrict__ es, const float* __restrict__ us,
                           float* __restrict__ out) {
    __shared__ float lx[4][256];                          // per-wave x row
    __shared__ float le[4][8][260];                       // per-wave staged embeds
    __shared__ int lcode[4][64];                          // per-wave cand codes

    const int tid = threadIdx.x, w = tid >> 6, lane = tid & 63;
    const int r = blockIdx.x * 4 + w;
    const int t16 = lane & 15;
    const float x2v = x2[r];
    const unsigned long long lt = (1ull << lane) - 1ull;

    // stage x row (wave-private; wave-lockstep + in-order LDS => no barrier)
    *(f32x4*)&lx[w][lane * 4] = *(const f32x4*)&x[r * D_DIM + lane * 4];

    uint4 kq = keys[r * 16 + t16];                        // 4 copies per 16-group
    unsigned kmin = kq.x & 0xFFFFF800u;
#pragma unroll
    for (int s = 1; s < 16; s <<= 1) {                    // gm over 16 tiles
        unsigned ok = __shfl_xor(kmin, s);
        kmin = ok < kmin ? ok : kmin;
    }
    const float thr = funkey(kmin) + DELTA;               // key-basis threshold

    // compact candidates (slot-major, deterministic ballot order)
    unsigned sv[4] = {kq.x, kq.y, kq.z, kq.w};
    int nc = 0;
#pragma unroll
    for (int s = 0; s < 4; ++s) {                         // static after unroll
        bool v = (lane < 16) && (funkey(sv[s] & 0xFFFFF800u) <= thr);
        unsigned long long b = __ballot(v);
        if (v) lcode[w][nc + __popcll(b & lt)] = (int)(sv[s] & 0x7FFu);
        nc += (int)__popcll(b);
    }
    bool resc = (lane < 16) && (funkey(kq.w & 0xFFFFF800u) <= thr);
    unsigned long long rmask = __ballot(resc);            // bits 0..15 = tiles

    float bv = __builtin_inff();
    int bi = 0x7FFFFFFF;
    auto lexmin = [&](float d2, int code) {
        if (d2 < bv || (d2 == bv && code < bi)) { bv = d2; bi = code; }
    };

#pragma unroll 1
    for (int g = 0; g < (nc + 7) >> 3; ++g) {             // wave-uniform nc
#pragma unroll
        for (int v = 0; v < 8; ++v) {                     // stage <=8 embed rows
            int idx = g * 8 + v;
            if (idx < nc) {
                int code = lcode[w][idx];
                *(f32x4*)&le[w][v][lane * 4] =
                    *(const f32x4*)&embed[code * D_DIM + lane * 4];
            }
        }
        int idx = g * 8 + lane;                           // lanes 0..7 run chains
        if (lane < 8 && idx < nc) {
            int code = lcode[w][idx];
            float t = 0.0f;
#pragma unroll 8
            for (int k4 = 0; k4 < 64; ++k4) {             // single chain, k ascending
                f32x4 a4 = *(const f32x4*)&lx[w][k4 * 4];     // broadcast
                f32x4 e4 = *(const f32x4*)&le[w][lane][k4 * 4];
                t = __builtin_fmaf(a4[0], e4[0], t);
                t = __builtin_fmaf(a4[1], e4[1], t);
                t = __builtin_fmaf(a4[2], e4[2], t);
                t = __builtin_fmaf(a4[3], e4[3], t);
            }
            lexmin((x2v - 2.0f * t) + e2[code], code);    // np op order
        }
    }

    // rare: >=4 codes within thr in one tile -> exact rescan of that tile
    while (rmask) {
        int t2 = __ffsll(rmask) - 1;
        rmask &= rmask - 1;
        int ca = t2 * 128 + lane, cb = ca + 64;
        float ta = 0.0f, tb = 0.0f;
#pragma unroll 8
        for (int k4 = 0; k4 < 64; ++k4) {                 // dual interleaved chains
            f32x4 a4 = *(const f32x4*)&lx[w][k4 * 4];
            f32x4 ea = *(const f32x4*)&embed[ca * D_DIM + k4 * 4];
            f32x4 eb = *(const f32x4*)&embed[cb * D_DIM + k4 * 4];
            ta = __builtin_fmaf(a4[0], ea[0], ta);
            tb = __builtin_fmaf(a4[0], eb[0], tb);
            ta = __builtin_fmaf(a4[1], ea[1], ta);
            tb = __builtin_fmaf(a4[1], eb[1], tb);
            ta = __builtin_fmaf(a4[2], ea[2], ta);
            tb = __builtin_fmaf(a4[2], eb[2], tb);
            ta = __builtin_fmaf(a4[3], ea[3], ta);
            tb = __builtin_fmaf(a4[3], eb[3], tb);
        }
        lexmin((x2v - 2.0f * ta) + e2[ca], ca);
        lexmin((x2v - 2.0f * tb) + e2[cb], cb);
    }

#pragma unroll
    for (int s = 1; s < 64; s <<= 1) {                    // 64-lane lex allreduce
        float ov = __shfl_xor(bv, s);
        int oi = __shfl_xor(bi, s);
        if (ov < bv || (ov == bv && oi < bi)) { bv = ov; bi = oi; }
    }
    if (lane == 0) out[r] = (float)bi;

    // fused gather: quantized[r] = es[bi]/max(us[bi],eps); 64 lanes x 4 floats
    float u = fmaxf(us[bi], VQ_EPS);
    f32x4 wv = *(const f32x4*)&es[bi * D_DIM + lane * 4];
    f32x4 o;
#pragma unroll
    for (int j = 0; j < 4; ++j) o[j] = wv[j] / u;         // IEEE div == np bitwise
    *(f32x4*)&out[N_ROWS + r * D_DIM + lane * 4] = o;
}

extern "C" void kernel_launch(void* const* d_in, const int* in_sizes, int n_in,
                              void* d_out, int out_size, void* d_ws, size_t ws_size,
                              hipStream_t stream) {
    const float* x = (const float*)d_in[0];               // [65536, 256]
    const float* es = (const float*)d_in[1];              // [2048, 256]
    const float* us = (const float*)d_in[2];              // [2048]
    float* out = (float*)d_out;

    char* w = (char*)d_ws;                                // total 53,747,712 B
    unsigned short* xswz = (unsigned short*)(w);                  // 33,554,432
    unsigned short* eswz = (unsigned short*)(w + 33554432);       //  1,048,576
    float* embed         = (float*)(w + 34603008);                //  2,097,152
    float* e2            = (float*)(w + 36700160);                //      8,192
    float* x2            = (float*)(w + 36708352);                //    262,144
    uint4* keys          = (uint4*)(w + 36970496);                // 16,777,216

    hipLaunchKernelGGL(prep_all, dim3(8448), dim3(256), 0, stream,
                       es, us, x, embed, eswz, e2, xswz, x2);
    hipLaunchKernelGGL(vq_scan, dim3(8192), dim3(256), 0, stream,
                       xswz, eswz, e2, keys);
    hipLaunchKernelGGL(vq_rescore, dim3(16384), dim3(256), 0, stream,
                       x, embed, e2, x2, keys, es, us, out);
}

// Round 21
// 204.660 us; speedup vs baseline: 1.3304x; 1.0117x over previous
//
#include <hip/hip_runtime.h>
#include <hip/hip_bf16.h>

// MimiEuclideanCodebook — SINGLE fp16-MFMA scan (gload_lds dbuf) with
// per-tile TOP-3 biased-positive packed-key epilogue (DPP rotate-merge,
// no atomics, deterministic) + barrier-free LDS-staged np-bit-exact rescore
// + fused gather.
// scan: per (row, 128-col tile) store three smallest packed keys
//   ((bits(s + 4096) & ~0x7F) | tile_local_code). s = e2 - 2*xe (x2 is
//   row-constant: ordering & within-row gaps preserved); +4096 makes all
//   values positive floats => u32 order == float order (no sign transform).
//   7-bit tile-local code => trunc slack <= 0.0625; DELTA 0.25 >= 2*err+slack.
// rescore (key-basis filter, exact fp32 decisions): thr = gm_trunc + DELTA.
//   Candidates = stored codes with deq <= thr. Tile rescan iff deq3 <= thr
//   (>=3 codes within thr in one tile; rare at fp16/0.25 density).
//   np-exact fp32 FMA chains from LDS; lex-(value,idx) min => np argmin.

typedef float f32x4 __attribute__((ext_vector_type(4)));
typedef short s16x8 __attribute__((ext_vector_type(8)));
typedef _Float16 h16x8 __attribute__((ext_vector_type(8)));

#define D_DIM 256
#define N_ROWS 65536
#define K_CODES 2048
#define VQ_EPS 1e-5f
#define DELTA 0.25f
#define KBIAS 4096.0f
#define KMASK 0xFFFFFF80u

__device__ __forceinline__ short f16s(float f) {
    _Float16 h = (_Float16)f;                             // RTN
    return __builtin_bit_cast(short, h);
}
__device__ __forceinline__ unsigned med3u(unsigned a, unsigned b, unsigned c) {
    unsigned d;
    asm("v_med3_u32 %0, %1, %2, %3" : "=v"(d) : "v"(a), "v"(b), "v"(c));
    return d;
}
__device__ __forceinline__ void gload16(const void* g, void* l) {
    __builtin_amdgcn_global_load_lds(
        (const __attribute__((address_space(1))) void*)g,
        (__attribute__((address_space(3))) void*)l, 16, 0, 0);
}

// DPP row_ror:N within each 16-lane row (VALU pipe; ctrl 0x120+N)
#define DPP_ROR(v, N) \
    ((unsigned)__builtin_amdgcn_update_dpp((int)(v), (int)(v), 0x120 + (N), 0xF, 0xF, true))

// numpy pairwise sum of squares over 256 (verified round 4)
__device__ __forceinline__ void np_sumsq_16lane(const float* a, float* out, int g) {
#pragma clang fp contract(off)
    int j = g & 7, h = g >> 3;
    const float* p = a + h * 128;
    float t = p[j];
    float r = t * t;
#pragma unroll
    for (int i = 1; i < 16; ++i) { float v = p[j + 8 * i]; r += v * v; }
    r += __shfl_xor(r, 1);
    r += __shfl_xor(r, 2);
    r += __shfl_xor(r, 4);
    float other = __shfl_xor(r, 8);
    if (g == 0) *out = r + other;
}

// FUSED prep (one launch): blocks <256 = codebook (embed=es/clip(us) IEEE div,
// fp16+swizzle eswz, np-pairwise e2); blocks >=256 = x (fp16+swizzle xswz,
// np-pairwise x2). All numerics identical to verified rounds.
__global__ void prep_all(const float* __restrict__ es, const float* __restrict__ us,
                         const float* __restrict__ x,
                         float* __restrict__ embed, unsigned short* __restrict__ eswz,
                         float* __restrict__ e2,
                         unsigned short* __restrict__ xswz, float* __restrict__ x2) {
    __shared__ float le[8][256];
    const int tid = threadIdx.x;
    if (blockIdx.x < 256) {                               // ---- codebook path
        const int rloc = tid >> 5, idx = tid & 31;        // 8 rows/block
        const int r = blockIdx.x * 8 + rloc;              // 2048 rows
        const float u = fmaxf(us[r], VQ_EPS);
        f32x4 v0 = *(const f32x4*)&es[r * D_DIM + idx * 8];
        f32x4 v1 = *(const f32x4*)&es[r * D_DIM + idx * 8 + 4];
        f32x4 e0, e1;
#pragma unroll
        for (int j = 0; j < 4; ++j) { e0[j] = v0[j] / u; e1[j] = v1[j] / u; }
        *(f32x4*)&embed[r * D_DIM + idx * 8] = e0;
        *(f32x4*)&embed[r * D_DIM + idx * 8 + 4] = e1;
        *(f32x4*)&le[rloc][idx * 8] = e0;
        *(f32x4*)&le[rloc][idx * 8 + 4] = e1;
        int kc = idx >> 2, ss = idx & 3;
        int sd = ss ^ ((r >> 1) & 3);                     // swizzle involution
        s16x8 b;
#pragma unroll
        for (int j = 0; j < 4; ++j) { b[j] = f16s(e0[j]); b[j + 4] = f16s(e1[j]); }
        *(s16x8*)&eswz[r * 256 + kc * 32 + sd * 8] = b;
        __syncthreads();
        if (idx < 16) np_sumsq_16lane(&le[rloc][0], &e2[r], idx);
    } else {                                              // ---- x path
        int gid = (blockIdx.x - 256) * 256 + tid;         // 65536*32
        int r = gid >> 5, idx = gid & 31;
        int kc = idx >> 2, s = idx & 3;
        int k0 = kc * 32 + (s ^ ((r >> 1) & 3)) * 8;
        const float* p = x + r * D_DIM + k0;
        s16x8 v;
#pragma unroll
        for (int j = 0; j < 8; ++j) v[j] = f16s(p[j]);
        *(s16x8*)&xswz[r * 256 + kc * 32 + s * 8] = v;
        if (idx < 16)                                     // L1-hot re-read
            np_sumsq_16lane(x + r * D_DIM, x2 + r, idx);
    }
}

// ---- single fp16 MFMA scan (dbuf gload_lds) — biased top-3, DPP merge -------
__launch_bounds__(256, 2)
__global__ void vq_scan(const unsigned short* __restrict__ xswz,
                        const unsigned short* __restrict__ eswz,
                        const float* __restrict__ e2,
                        uint2* __restrict__ keys2, unsigned* __restrict__ keys3) {
    __shared__ __align__(16) short lds[2][2][4096];       // [buf][A/B][8KB]

    const int bid = blockIdx.x;
    const int swz = (bid & 7) * 1024 + (bid >> 3);        // XCD-contiguous tiles
    const int mt = swz >> 4, nt = swz & 15;
    const int m_base = mt * 128, n_base = nt * 128;
    const int tid = threadIdx.x, lane = tid & 63, wid = tid >> 6;
    const int rb = wid * 32;                              // wave: rows rb..rb+31
    const int l15 = lane & 15, lg = lane >> 4;

    f32x4 acc[2][8];
#pragma unroll
    for (int m = 0; m < 2; ++m)
#pragma unroll
        for (int n = 0; n < 8; ++n) { f32x4 z = {0.f, 0.f, 0.f, 0.f}; acc[m][n] = z; }

    auto stage = [&](int buf, int kc) {
#pragma unroll
        for (int i = 0; i < 2; ++i) {
            int off = i * 4096 + wid * 1024 + lane * 16;  // linear LDS dest bytes
            int row = off >> 6, slot = (off >> 4) & 3;    // pre-permuted source
            gload16((const char*)xswz + (((size_t)(m_base + row)) << 9) + (kc << 6) + (slot << 4),
                    (char*)&lds[buf][0][0] + off);
            gload16((const char*)eswz + (((size_t)(n_base + row)) << 9) + (kc << 6) + (slot << 4),
                    (char*)&lds[buf][1][0] + off);
        }
    };
    auto compute = [&](int buf) {
        const short* A = &lds[buf][0][0];
        const short* B = &lds[buf][1][0];
        h16x8 af[2], bf[8];
#pragma unroll
        for (int m = 0; m < 2; ++m) {
            int R = rb + m * 16 + l15, s = lg ^ ((R >> 1) & 3);
            af[m] = __builtin_bit_cast(h16x8, *(const s16x8*)&A[R * 32 + s * 8]);
        }
#pragma unroll
        for (int n = 0; n < 8; ++n) {
            int R = n * 16 + l15, s = lg ^ ((R >> 1) & 3);
            bf[n] = __builtin_bit_cast(h16x8, *(const s16x8*)&B[R * 32 + s * 8]);
        }
#pragma unroll
        for (int m = 0; m < 2; ++m)
#pragma unroll
            for (int n = 0; n < 8; ++n)
                acc[m][n] = __builtin_amdgcn_mfma_f32_16x16x32_f16(af[m], bf[n], acc[m][n], 0, 0, 0);
    };

    stage(0, 0);
    __syncthreads();
#pragma unroll 1
    for (int kc = 0; kc < 8; ++kc) {
        if (kc < 7) stage((kc + 1) & 1, kc + 1);          // loads fly under compute
        compute(kc & 1);
        __syncthreads();                                  // drain gload + readers done
    }

    // epilogue: sv = fma(-2, xe, e2 + 4096) — positive float => u32-ordered.
    // pk = (bits & ~0x7F) | (n*16+l15)  (7-bit tile-local code).
    // Per-lane sorted top-3 insert (min + 2 med3); DPP row_ror {8,4,2,1}
    // rotate-merge (3-list bitonic merge + sort-3), all VALU-pipe.
    // C/D layout (rounds 8/10 verified): col = n*16 + l15, row = lg*4+j (+m*16)
    const int grow0 = m_base + rb + lg * 4;
    float e2b[8];
#pragma unroll
    for (int n = 0; n < 8; ++n) e2b[n] = e2[n_base + n * 16 + l15] + KBIAS;

#pragma unroll
    for (int m = 0; m < 2; ++m) {
#pragma unroll
        for (int j = 0; j < 4; ++j) {
            int gr = grow0 + m * 16 + j;
            unsigned k1 = 0xFFFFFFFFu, k2 = 0xFFFFFFFFu, k3 = 0xFFFFFFFFu;
#pragma unroll
            for (int n = 0; n < 8; ++n) {
                float sv = __builtin_fmaf(-2.0f, acc[m][n][j], e2b[n]);
                unsigned pk = (__float_as_uint(sv) & KMASK)
                              | (unsigned)(n * 16 + l15);
                unsigned n1 = min(pk, k1);                // med3 sorted insert
                unsigned n2 = med3u(pk, k1, k2);
                unsigned n3 = med3u(pk, k2, k3);
                k1 = n1; k2 = n2; k3 = n3;
            }
#define MERGE_STEP(RR)                                                         \
            {                                                                  \
                unsigned o1 = DPP_ROR(k1, RR), o2 = DPP_ROR(k2, RR);           \
                unsigned o3 = DPP_ROR(k3, RR);                                 \
                unsigned c1 = min(k1, o3), c2 = min(k2, o2), c3 = min(k3, o1); \
                unsigned t;                                                    \
                t = min(c1, c2); c2 = max(c1, c2); c1 = t;                     \
                t = min(c2, c3); c3 = max(c2, c3); c2 = t;                     \
                t = min(c1, c2); c2 = max(c1, c2); c1 = t;                     \
                k1 = c1; k2 = c2; k3 = c3;                                     \
            }
            MERGE_STEP(8)
            MERGE_STEP(4)
            MERGE_STEP(2)
            MERGE_STEP(1)
#undef MERGE_STEP
            if (l15 == 0) {
                uint2 kq; kq.x = k1; kq.y = k2;
                keys2[gr * 16 + nt] = kq;
                keys3[gr * 16 + nt] = k3;
            }
        }
    }
}

// -- barrier-free LDS-staged np-exact rescore (wave per row) + fused gather ----
__launch_bounds__(256, 4)
__global__ void vq_rescore(const float* __restrict__ x, const float* __restrict__ embed,
                           const float* __restrict__ e2, const float* __restrict__ x2,
                           const uint2* __restrict__ keys2,
                           const unsigned* __restrict__ keys3,
                           const float* __restrict__ es, const float* __restrict__ us,
                           float* __restrict__ out) {
    __shared__ float lx[4][256];                          // per-wave x row
    __shared__ float le[4][8][260];                       // per-wave staged embeds
    __shared__ int lcode[4][64];                          // per-wave cand codes

    const int tid = threadIdx.x, w = tid >> 6, lane = tid & 63;
    const int r = blockIdx.x * 4 + w;
    const int t16 = lane & 15;
    const float x2v = x2[r];
    const unsigned long long lt = (1ull << lane) - 1ull;

    // stage x row (wave-private; wave-lockstep + in-order LDS => no barrier)
    *(f32x4*)&lx[w][lane * 4] = *(const f32x4*)&x[r * D_DIM + lane * 4];

    uint2 k12 = keys2[r * 16 + t16];                      // 4 copies per 16-group
    unsigned k3v = keys3[r * 16 + t16];
    unsigned kmin = k12.x & KMASK;
#pragma unroll
    for (int s = 1; s < 16; s <<= 1) {                    // gm over 16 tiles
        unsigned ok = __shfl_xor(kmin, s);
        kmin = ok < kmin ? ok : kmin;
    }
    const float thr = __uint_as_float(kmin) + DELTA;      // biased-key basis

    // compact candidates (slot-major, deterministic ballot order)
    unsigned sv[3] = {k12.x, k12.y, k3v};
    int nc = 0;
#pragma unroll
    for (int s = 0; s < 3; ++s) {                         // static after unroll
        bool v = (lane < 16) && (__uint_as_float(sv[s] & KMASK) <= thr);
        unsigned long long b = __ballot(v);
        if (v) lcode[w][nc + __popcll(b & lt)] =
                   (int)(sv[s] & 0x7Fu) + t16 * 128;      // tile-local -> global
        nc += (int)__popcll(b);
    }
    bool resc = (lane < 16) && (__uint_as_float(k3v & KMASK) <= thr);
    unsigned long long rmask = __ballot(resc);            // bits 0..15 = tiles

    float bv = __builtin_inff();
    int bi = 0x7FFFFFFF;
    auto lexmin = [&](float d2, int code) {
        if (d2 < bv || (d2 == bv && code < bi)) { bv = d2; bi = code; }
    };

#pragma unroll 1
    for (int g = 0; g < (nc + 7) >> 3; ++g) {             // wave-uniform nc
#pragma unroll
        for (int v = 0; v < 8; ++v) {                     // stage <=8 embed rows
            int idx = g * 8 + v;
            if (idx < nc) {
                int code = lcode[w][idx];
                *(f32x4*)&le[w][v][lane * 4] =
                    *(const f32x4*)&embed[code * D_DIM + lane * 4];
            }
        }
        int idx = g * 8 + lane;                           // lanes 0..7 run chains
        if (lane < 8 && idx < nc) {
            int code = lcode[w][idx];
            float t = 0.0f;
#pragma unroll 8
            for (int k4 = 0; k4 < 64; ++k4) {             // single chain, k ascending
                f32x4 a4 = *(const f32x4*)&lx[w][k4 * 4];     // broadcast
                f32x4 e4 = *(const f32x4*)&le[w][lane][k4 * 4];
                t = __builtin_fmaf(a4[0], e4[0], t);
                t = __builtin_fmaf(a4[1], e4[1], t);
                t = __builtin_fmaf(a4[2], e4[2], t);
                t = __builtin_fmaf(a4[3], e4[3], t);
            }
            lexmin((x2v - 2.0f * t) + e2[code], code);    // np op order
        }
    }

    // rare: >=3 codes within thr in one tile -> exact rescan of that tile
    while (rmask) {
        int t2 = __ffsll(rmask) - 1;
        rmask &= rmask - 1;
        int ca = t2 * 128 + lane, cb = ca + 64;
        float ta = 0.0f, tb = 0.0f;
#pragma unroll 8
        for (int k4 = 0; k4 < 64; ++k4) {                 // dual interleaved chains
            f32x4 a4 = *(const f32x4*)&lx[w][k4 * 4];
            f32x4 ea = *(const f32x4*)&embed[ca * D_DIM + k4 * 4];
            f32x4 eb = *(const f32x4*)&embed[cb * D_DIM + k4 * 4];
            ta = __builtin_fmaf(a4[0], ea[0], ta);
            tb = __builtin_fmaf(a4[0], eb[0], tb);
            ta = __builtin_fmaf(a4[1], ea[1], ta);
            tb = __builtin_fmaf(a4[1], eb[1], tb);
            ta = __builtin_fmaf(a4[2], ea[2], ta);
            tb = __builtin_fmaf(a4[2], eb[2], tb);
            ta = __builtin_fmaf(a4[3], ea[3], ta);
            tb = __builtin_fmaf(a4[3], eb[3], tb);
        }
        lexmin((x2v - 2.0f * ta) + e2[ca], ca);
        lexmin((x2v - 2.0f * tb) + e2[cb], cb);
    }

#pragma unroll
    for (int s = 1; s < 64; s <<= 1) {                    // 64-lane lex allreduce
        float ov = __shfl_xor(bv, s);
        int oi = __shfl_xor(bi, s);
        if (ov < bv || (ov == bv && oi < bi)) { bv = ov; bi = oi; }
    }
    if (lane == 0) out[r] = (float)bi;

    // fused gather: quantized[r] = es[bi]/max(us[bi],eps); 64 lanes x 4 floats
    float u = fmaxf(us[bi], VQ_EPS);
    f32x4 wv = *(const f32x4*)&es[bi * D_DIM + lane * 4];
    f32x4 o;
#pragma unroll
    for (int j = 0; j < 4; ++j) o[j] = wv[j] / u;         // IEEE div == np bitwise
    *(f32x4*)&out[N_ROWS + r * D_DIM + lane * 4] = o;
}

extern "C" void kernel_launch(void* const* d_in, const int* in_sizes, int n_in,
                              void* d_out, int out_size, void* d_ws, size_t ws_size,
                              hipStream_t stream) {
    const float* x = (const float*)d_in[0];               // [65536, 256]
    const float* es = (const float*)d_in[1];              // [2048, 256]
    const float* us = (const float*)d_in[2];              // [2048]
    float* out = (float*)d_out;

    char* w = (char*)d_ws;                                // total 49,553,408 B
    unsigned short* xswz = (unsigned short*)(w);                  // 33,554,432
    unsigned short* eswz = (unsigned short*)(w + 33554432);       //  1,048,576
    float* embed         = (float*)(w + 34603008);                //  2,097,152
    float* e2            = (float*)(w + 36700160);                //      8,192
    float* x2            = (float*)(w + 36708352);                //    262,144
    uint2* keys2         = (uint2*)(w + 36970496);                //  8,388,608
    unsigned* keys3      = (unsigned*)(w + 45359104);             //  4,194,304

    hipLaunchKernelGGL(prep_all, dim3(8448), dim3(256), 0, stream,
                       es, us, x, embed, eswz, e2, xswz, x2);
    hipLaunchKernelGGL(vq_scan, dim3(8192), dim3(256), 0, stream,
                       xswz, eswz, e2, keys2, keys3);
    hipLaunchKernelGGL(vq_rescore, dim3(16384), dim3(256), 0, stream,
                       x, embed, e2, x2, keys2, keys3, es, us, out);
}

// Round 22
// 200.386 us; speedup vs baseline: 1.3588x; 1.0213x over previous
//
#include <hip/hip_runtime.h>
#include <hip/hip_bf16.h>

// MimiEuclideanCodebook — SINGLE fp16-MFMA scan (gload_lds dbuf) with
// per-tile TOP-4 biased-positive packed-key epilogue (DPP rotate-merge,
// no atomics, deterministic) + barrier-free LDS-staged np-bit-exact rescore
// + fused gather.
// scan: per (row, 128-col tile) store uint4 = four smallest packed keys
//   ((bits(s + 4096) & ~0x7F) | tile_local_code). s = e2 - 2*xe (x2 is
//   row-constant: ordering & within-row gaps preserved); +4096 makes all
//   values positive floats => u32 order == float order (no sign transform).
//   7-bit tile-local code => trunc slack <= 0.0625; DELTA 0.25 >= 2*err+slack.
// rescore (key-basis filter, exact fp32 decisions): thr = gm_trunc + DELTA.
//   Candidates = stored codes with deq <= thr. Tile rescan iff deq4 <= thr
//   (>=4 codes within thr in one tile; rare — round-16/20-verified rate).
//   np-exact fp32 FMA chains from LDS; lex-(value,idx) min => np argmin.

typedef float f32x4 __attribute__((ext_vector_type(4)));
typedef short s16x8 __attribute__((ext_vector_type(8)));
typedef _Float16 h16x8 __attribute__((ext_vector_type(8)));

#define D_DIM 256
#define N_ROWS 65536
#define K_CODES 2048
#define VQ_EPS 1e-5f
#define DELTA 0.25f
#define KBIAS 4096.0f
#define KMASK 0xFFFFFF80u

__device__ __forceinline__ short f16s(float f) {
    _Float16 h = (_Float16)f;                             // RTN
    return __builtin_bit_cast(short, h);
}
__device__ __forceinline__ unsigned med3u(unsigned a, unsigned b, unsigned c) {
    unsigned d;
    asm("v_med3_u32 %0, %1, %2, %3" : "=v"(d) : "v"(a), "v"(b), "v"(c));
    return d;
}
__device__ __forceinline__ void gload16(const void* g, void* l) {
    __builtin_amdgcn_global_load_lds(
        (const __attribute__((address_space(1))) void*)g,
        (__attribute__((address_space(3))) void*)l, 16, 0, 0);
}

// DPP row_ror:N within each 16-lane row (VALU pipe; ctrl 0x120+N)
#define DPP_ROR(v, N) \
    ((unsigned)__builtin_amdgcn_update_dpp((int)(v), (int)(v), 0x120 + (N), 0xF, 0xF, true))

// numpy pairwise sum of squares over 256 (verified round 4)
__device__ __forceinline__ void np_sumsq_16lane(const float* a, float* out, int g) {
#pragma clang fp contract(off)
    int j = g & 7, h = g >> 3;
    const float* p = a + h * 128;
    float t = p[j];
    float r = t * t;
#pragma unroll
    for (int i = 1; i < 16; ++i) { float v = p[j + 8 * i]; r += v * v; }
    r += __shfl_xor(r, 1);
    r += __shfl_xor(r, 2);
    r += __shfl_xor(r, 4);
    float other = __shfl_xor(r, 8);
    if (g == 0) *out = r + other;
}

// FUSED prep (one launch): blocks <256 = codebook (embed=es/clip(us) IEEE div,
// fp16+swizzle eswz, np-pairwise e2); blocks >=256 = x (fp16+swizzle xswz,
// np-pairwise x2). All numerics identical to verified rounds.
__global__ void prep_all(const float* __restrict__ es, const float* __restrict__ us,
                         const float* __restrict__ x,
                         float* __restrict__ embed, unsigned short* __restrict__ eswz,
                         float* __restrict__ e2,
                         unsigned short* __restrict__ xswz, float* __restrict__ x2) {
    __shared__ float le[8][256];
    const int tid = threadIdx.x;
    if (blockIdx.x < 256) {                               // ---- codebook path
        const int rloc = tid >> 5, idx = tid & 31;        // 8 rows/block
        const int r = blockIdx.x * 8 + rloc;              // 2048 rows
        const float u = fmaxf(us[r], VQ_EPS);
        f32x4 v0 = *(const f32x4*)&es[r * D_DIM + idx * 8];
        f32x4 v1 = *(const f32x4*)&es[r * D_DIM + idx * 8 + 4];
        f32x4 e0, e1;
#pragma unroll
        for (int j = 0; j < 4; ++j) { e0[j] = v0[j] / u; e1[j] = v1[j] / u; }
        *(f32x4*)&embed[r * D_DIM + idx * 8] = e0;
        *(f32x4*)&embed[r * D_DIM + idx * 8 + 4] = e1;
        *(f32x4*)&le[rloc][idx * 8] = e0;
        *(f32x4*)&le[rloc][idx * 8 + 4] = e1;
        int kc = idx >> 2, ss = idx & 3;
        int sd = ss ^ ((r >> 1) & 3);                     // swizzle involution
        s16x8 b;
#pragma unroll
        for (int j = 0; j < 4; ++j) { b[j] = f16s(e0[j]); b[j + 4] = f16s(e1[j]); }
        *(s16x8*)&eswz[r * 256 + kc * 32 + sd * 8] = b;
        __syncthreads();
        if (idx < 16) np_sumsq_16lane(&le[rloc][0], &e2[r], idx);
    } else {                                              // ---- x path
        int gid = (blockIdx.x - 256) * 256 + tid;         // 65536*32
        int r = gid >> 5, idx = gid & 31;
        int kc = idx >> 2, s = idx & 3;
        int k0 = kc * 32 + (s ^ ((r >> 1) & 3)) * 8;
        const float* p = x + r * D_DIM + k0;
        s16x8 v;
#pragma unroll
        for (int j = 0; j < 8; ++j) v[j] = f16s(p[j]);
        *(s16x8*)&xswz[r * 256 + kc * 32 + s * 8] = v;
        if (idx < 16)                                     // L1-hot re-read
            np_sumsq_16lane(x + r * D_DIM, x2 + r, idx);
    }
}

// ---- single fp16 MFMA scan (dbuf gload_lds) — biased top-4, DPP merge -------
__launch_bounds__(256, 2)
__global__ void vq_scan(const unsigned short* __restrict__ xswz,
                        const unsigned short* __restrict__ eswz,
                        const float* __restrict__ e2,
                        uint4* __restrict__ keys) {
    __shared__ __align__(16) short lds[2][2][4096];       // [buf][A/B][8KB]

    const int bid = blockIdx.x;
    const int swz = (bid & 7) * 1024 + (bid >> 3);        // XCD-contiguous tiles
    const int mt = swz >> 4, nt = swz & 15;
    const int m_base = mt * 128, n_base = nt * 128;
    const int tid = threadIdx.x, lane = tid & 63, wid = tid >> 6;
    const int rb = wid * 32;                              // wave: rows rb..rb+31
    const int l15 = lane & 15, lg = lane >> 4;

    f32x4 acc[2][8];
#pragma unroll
    for (int m = 0; m < 2; ++m)
#pragma unroll
        for (int n = 0; n < 8; ++n) { f32x4 z = {0.f, 0.f, 0.f, 0.f}; acc[m][n] = z; }

    auto stage = [&](int buf, int kc) {
#pragma unroll
        for (int i = 0; i < 2; ++i) {
            int off = i * 4096 + wid * 1024 + lane * 16;  // linear LDS dest bytes
            int row = off >> 6, slot = (off >> 4) & 3;    // pre-permuted source
            gload16((const char*)xswz + (((size_t)(m_base + row)) << 9) + (kc << 6) + (slot << 4),
                    (char*)&lds[buf][0][0] + off);
            gload16((const char*)eswz + (((size_t)(n_base + row)) << 9) + (kc << 6) + (slot << 4),
                    (char*)&lds[buf][1][0] + off);
        }
    };
    auto compute = [&](int buf) {
        const short* A = &lds[buf][0][0];
        const short* B = &lds[buf][1][0];
        h16x8 af[2], bf[8];
#pragma unroll
        for (int m = 0; m < 2; ++m) {
            int R = rb + m * 16 + l15, s = lg ^ ((R >> 1) & 3);
            af[m] = __builtin_bit_cast(h16x8, *(const s16x8*)&A[R * 32 + s * 8]);
        }
#pragma unroll
        for (int n = 0; n < 8; ++n) {
            int R = n * 16 + l15, s = lg ^ ((R >> 1) & 3);
            bf[n] = __builtin_bit_cast(h16x8, *(const s16x8*)&B[R * 32 + s * 8]);
        }
#pragma unroll
        for (int m = 0; m < 2; ++m)
#pragma unroll
            for (int n = 0; n < 8; ++n)
                acc[m][n] = __builtin_amdgcn_mfma_f32_16x16x32_f16(af[m], bf[n], acc[m][n], 0, 0, 0);
    };

    stage(0, 0);
    __syncthreads();
#pragma unroll 1
    for (int kc = 0; kc < 8; ++kc) {
        if (kc < 7) stage((kc + 1) & 1, kc + 1);          // loads fly under compute
        compute(kc & 1);
        __syncthreads();                                  // drain gload + readers done
    }

    // epilogue: sv = fma(-2, xe, e2 + 4096) — positive float => u32-ordered.
    // pk = (bits & ~0x7F) | (n*16+l15)  (7-bit tile-local code).
    // Per-lane sorted top-4 insert (min + 3 med3); DPP row_ror {8,4,2,1}
    // rotate-merge (4-list bitonic merge network), all VALU-pipe.
    // C/D layout (rounds 8/10 verified): col = n*16 + l15, row = lg*4+j (+m*16)
    const int grow0 = m_base + rb + lg * 4;
    float e2b[8];
#pragma unroll
    for (int n = 0; n < 8; ++n) e2b[n] = e2[n_base + n * 16 + l15] + KBIAS;

#pragma unroll
    for (int m = 0; m < 2; ++m) {
#pragma unroll
        for (int j = 0; j < 4; ++j) {
            int gr = grow0 + m * 16 + j;
            unsigned k1 = 0xFFFFFFFFu, k2 = 0xFFFFFFFFu;
            unsigned k3 = 0xFFFFFFFFu, k4 = 0xFFFFFFFFu;
#pragma unroll
            for (int n = 0; n < 8; ++n) {
                float sv = __builtin_fmaf(-2.0f, acc[m][n][j], e2b[n]);
                unsigned pk = (__float_as_uint(sv) & KMASK)
                              | (unsigned)(n * 16 + l15);
                unsigned n1 = min(pk, k1);                // med3 sorted insert
                unsigned n2 = med3u(pk, k1, k2);
                unsigned n3 = med3u(pk, k2, k3);
                unsigned n4 = med3u(pk, k3, k4);
                k1 = n1; k2 = n2; k3 = n3; k4 = n4;
            }
#define MERGE_STEP(RR)                                                         \
            {                                                                  \
                unsigned o1 = DPP_ROR(k1, RR), o2 = DPP_ROR(k2, RR);           \
                unsigned o3 = DPP_ROR(k3, RR), o4 = DPP_ROR(k4, RR);           \
                unsigned c1 = min(k1, o4), c2 = min(k2, o3);                   \
                unsigned c3 = min(k3, o2), c4 = min(k4, o1);                   \
                unsigned t;                                                    \
                t = min(c1, c3); c3 = max(c1, c3); c1 = t;                     \
                t = min(c2, c4); c4 = max(c2, c4); c2 = t;                     \
                t = min(c1, c2); c2 = max(c1, c2); c1 = t;                     \
                t = min(c3, c4); c4 = max(c3, c4); c3 = t;                     \
                k1 = c1; k2 = c2; k3 = c3; k4 = c4;                            \
            }
            MERGE_STEP(8)
            MERGE_STEP(4)
            MERGE_STEP(2)
            MERGE_STEP(1)
#undef MERGE_STEP
            if (l15 == 0) {
                uint4 kq; kq.x = k1; kq.y = k2; kq.z = k3; kq.w = k4;
                keys[gr * 16 + nt] = kq;
            }
        }
    }
}

// -- barrier-free LDS-staged np-exact rescore (wave per row) + fused gather ----
__launch_bounds__(256, 4)
__global__ void vq_rescore(const float* __restrict__ x, const float* __restrict__ embed,
                           const float* __restrict__ e2, const float* __restrict__ x2,
                           const uint4* __restrict__ keys,
                           const float* __restrict__ es, const float* __restrict__ us,
                           float* __restrict__ out) {
    __shared__ float lx[4][256];                          // per-wave x row
    __shared__ float le[4][8][260];                       // per-wave staged embeds
    __shared__ int lcode[4][64];                          // per-wave cand codes

    const int tid = threadIdx.x, w = tid >> 6, lane = tid & 63;
    const int r = blockIdx.x * 4 + w;
    const int t16 = lane & 15;
    const float x2v = x2[r];
    const unsigned long long lt = (1ull << lane) - 1ull;

    // stage x row (wave-private; wave-lockstep + in-order LDS => no barrier)
    *(f32x4*)&lx[w][lane * 4] = *(const f32x4*)&x[r * D_DIM + lane * 4];

    uint4 kq = keys[r * 16 + t16];                        // 4 copies per 16-group
    unsigned kmin = kq.x & KMASK;
#pragma unroll
    for (int s = 1; s < 16; s <<= 1) {                    // gm over 16 tiles
        unsigned ok = __shfl_xor(kmin, s);
        kmin = ok < kmin ? ok : kmin;
    }
    const float thr = __uint_as_float(kmin) + DELTA;      // biased-key basis

    // compact candidates (slot-major, deterministic ballot order)
    unsigned sv[4] = {kq.x, kq.y, kq.z, kq.w};
    int nc = 0;
#pragma unroll
    for (int s = 0; s < 4; ++s) {                         // static after unroll
        bool v = (lane < 16) && (__uint_as_float(sv[s] & KMASK) <= thr);
        unsigned long long b = __ballot(v);
        if (v) lcode[w][nc + __popcll(b & lt)] =
                   (int)(sv[s] & 0x7Fu) + t16 * 128;      // tile-local -> global
        nc += (int)__popcll(b);
    }
    bool resc = (lane < 16) && (__uint_as_float(kq.w & KMASK) <= thr);
    unsigned long long rmask = __ballot(resc);            // bits 0..15 = tiles

    float bv = __builtin_inff();
    int bi = 0x7FFFFFFF;
    auto lexmin = [&](float d2, int code) {
        if (d2 < bv || (d2 == bv && code < bi)) { bv = d2; bi = code; }
    };

#pragma unroll 1
    for (int g = 0; g < (nc + 7) >> 3; ++g) {             // wave-uniform nc
#pragma unroll
        for (int v = 0; v < 8; ++v) {                     // stage <=8 embed rows
            int idx = g * 8 + v;
            if (idx < nc) {
                int code = lcode[w][idx];
                *(f32x4*)&le[w][v][lane * 4] =
                    *(const f32x4*)&embed[code * D_DIM + lane * 4];
            }
        }
        int idx = g * 8 + lane;                           // lanes 0..7 run chains
        if (lane < 8 && idx < nc) {
            int code = lcode[w][idx];
            float t = 0.0f;
#pragma unroll 8
            for (int k4 = 0; k4 < 64; ++k4) {             // single chain, k ascending
                f32x4 a4 = *(const f32x4*)&lx[w][k4 * 4];     // broadcast
                f32x4 e4 = *(const f32x4*)&le[w][lane][k4 * 4];
                t = __builtin_fmaf(a4[0], e4[0], t);
                t = __builtin_fmaf(a4[1], e4[1], t);
                t = __builtin_fmaf(a4[2], e4[2], t);
                t = __builtin_fmaf(a4[3], e4[3], t);
            }
            lexmin((x2v - 2.0f * t) + e2[code], code);    // np op order
        }
    }

    // rare: >=4 codes within thr in one tile -> exact rescan of that tile
    while (rmask) {
        int t2 = __ffsll(rmask) - 1;
        rmask &= rmask - 1;
        int ca = t2 * 128 + lane, cb = ca + 64;
        float ta = 0.0f, tb = 0.0f;
#pragma unroll 8
        for (int k4 = 0; k4 < 64; ++k4) {                 // dual interleaved chains
            f32x4 a4 = *(const f32x4*)&lx[w][k4 * 4];
            f32x4 ea = *(const f32x4*)&embed[ca * D_DIM + k4 * 4];
            f32x4 eb = *(const f32x4*)&embed[cb * D_DIM + k4 * 4];
            ta = __builtin_fmaf(a4[0], ea[0], ta);
            tb = __builtin_fmaf(a4[0], eb[0], tb);
            ta = __builtin_fmaf(a4[1], ea[1], ta);
            tb = __builtin_fmaf(a4[1], eb[1], tb);
            ta = __builtin_fmaf(a4[2], ea[2], ta);
            tb = __builtin_fmaf(a4[2], eb[2], tb);
            ta = __builtin_fmaf(a4[3], ea[3], ta);
            tb = __builtin_fmaf(a4[3], eb[3], tb);
        }
        lexmin((x2v - 2.0f * ta) + e2[ca], ca);
        lexmin((x2v - 2.0f * tb) + e2[cb], cb);
    }

#pragma unroll
    for (int s = 1; s < 64; s <<= 1) {                    // 64-lane lex allreduce
        float ov = __shfl_xor(bv, s);
        int oi = __shfl_xor(bi, s);
        if (ov < bv || (ov == bv && oi < bi)) { bv = ov; bi = oi; }
    }
    if (lane == 0) out[r] = (float)bi;

    // fused gather: quantized[r] = es[bi]/max(us[bi],eps); 64 lanes x 4 floats
    float u = fmaxf(us[bi], VQ_EPS);
    f32x4 wv = *(const f32x4*)&es[bi * D_DIM + lane * 4];
    f32x4 o;
#pragma unroll
    for (int j = 0; j < 4; ++j) o[j] = wv[j] / u;         // IEEE div == np bitwise
    *(f32x4*)&out[N_ROWS + r * D_DIM + lane * 4] = o;
}

extern "C" void kernel_launch(void* const* d_in, const int* in_sizes, int n_in,
                              void* d_out, int out_size, void* d_ws, size_t ws_size,
                              hipStream_t stream) {
    const float* x = (const float*)d_in[0];               // [65536, 256]
    const float* es = (const float*)d_in[1];              // [2048, 256]
    const float* us = (const float*)d_in[2];              // [2048]
    float* out = (float*)d_out;

    char* w = (char*)d_ws;                                // total 53,747,712 B
    unsigned short* xswz = (unsigned short*)(w);                  // 33,554,432
    unsigned short* eswz = (unsigned short*)(w + 33554432);       //  1,048,576
    float* embed         = (float*)(w + 34603008);                //  2,097,152
    float* e2            = (float*)(w + 36700160);                //      8,192
    float* x2            = (float*)(w + 36708352);                //    262,144
    uint4* keys          = (uint4*)(w + 36970496);                // 16,777,216

    hipLaunchKernelGGL(prep_all, dim3(8448), dim3(256), 0, stream,
                       es, us, x, embed, eswz, e2, xswz, x2);
    hipLaunchKernelGGL(vq_scan, dim3(8192), dim3(256), 0, stream,
                       xswz, eswz, e2, keys);
    hipLaunchKernelGGL(vq_rescore, dim3(16384), dim3(256), 0, stream,
                       x, embed, e2, x2, keys, es, us, out);
}